// Round 15
// baseline (511.827 us; speedup 1.0000x reference)
//
#include <hip/hip_runtime.h>

#define N_NODES 80000
#define N_EDGES 1280000
#define NNZ (N_EDGES + N_NODES)
#define DIM 128
#define HD3 64
#define GROUP 40
#define NPOOL (N_NODES / GROUP)   // 2000
#define L1DIM 512
#define L2DIM 256
#define OUTD 10
#define SPLITK 4
#define L1K (HD3 * GROUP)          // 2560

#define SCAN_BLK 1024
#define SCAN_NB ((N_NODES + SCAN_BLK - 1) / SCAN_BLK)  // 79

// bucket sort for CSR build
#define NB_BUCKETS ((N_NODES + 255) >> 8)              // 313
#define NB_PAD 320
#define EPB 8192
#define NBLK ((NNZ + EPB - 1) / EPB)                   // 167

typedef unsigned int u32;
typedef unsigned short u16;
typedef __bf16 bf16x8 __attribute__((ext_vector_type(8)));
typedef float f32x4 __attribute__((ext_vector_type(4)));
typedef float f32x2 __attribute__((ext_vector_type(2)));

__device__ __forceinline__ float lrelu(float v, float s) { return v > 0.f ? v : s * v; }

__device__ __forceinline__ float b2f(u16 b) {
    u32 u = ((u32)b) << 16;
    float f; __builtin_memcpy(&f, &u, 4); return f;
}
__device__ __forceinline__ u16 f2b(float f) {
    u32 u; __builtin_memcpy(&u, &f, 4);
    return (u16)((u + 0x7fffu + ((u >> 16) & 1u)) >> 16);
}
// unpack a bf16 pair (u32) into f32x2 {lo, hi}
__device__ __forceinline__ f32x2 bf2(u32 v) {
    f32x2 r;
    r.x = __uint_as_float(v << 16);
    r.y = __uint_as_float(v & 0xffff0000u);
    return r;
}

// ---------------- CSR build: two-level bucket sort ----------------

__global__ __launch_bounds__(256) void k_hist(const int* __restrict__ ei, u32* __restrict__ cnt) {
    __shared__ u32 h[NB_PAD];
    for (int i = threadIdx.x; i < NB_PAD; i += 256) h[i] = 0;
    __syncthreads();
    int base = blockIdx.x * EPB;
    #pragma unroll 4
    for (int i = 0; i < EPB / 256; ++i) {
        int idx = base + i * 256 + threadIdx.x;
        if (idx < NNZ) {
            int d = (idx < N_EDGES) ? ei[N_EDGES + idx] : idx - N_EDGES;
            atomicAdd(&h[d >> 8], 1u);
        }
    }
    __syncthreads();
    for (int b = threadIdx.x; b < NB_BUCKETS; b += 256)
        cnt[blockIdx.x * NB_PAD + b] = h[b];
}

__global__ __launch_bounds__(256) void k_bscan_col(const u32* __restrict__ cnt,
                                                   u32* __restrict__ basep,
                                                   u32* __restrict__ btot) {
    int b = blockIdx.x, t = threadIdx.x;
    u32 v = (t < NBLK) ? cnt[t * NB_PAD + b] : 0;
    __shared__ u32 sm[256];
    sm[t] = v; __syncthreads();
    for (int off = 1; off < 256; off <<= 1) {
        u32 u = (t >= off) ? sm[t - off] : 0; __syncthreads();
        sm[t] += u; __syncthreads();
    }
    if (t < NBLK) basep[t * NB_PAD + b] = sm[t] - v;
    if (t == 255) btot[b] = sm[255];
}

__global__ __launch_bounds__(512) void k_bscan_top(const u32* __restrict__ btot,
                                                   u32* __restrict__ bbase) {
    __shared__ u32 sm[512];
    int t = threadIdx.x;
    u32 v = (t < NB_BUCKETS) ? btot[t] : 0;
    sm[t] = v; __syncthreads();
    for (int off = 1; off < 512; off <<= 1) {
        u32 u = (t >= off) ? sm[t - off] : 0; __syncthreads();
        sm[t] += u; __syncthreads();
    }
    if (t < NB_BUCKETS) bbase[t] = sm[t] - v;
    if (t == NB_BUCKETS - 1) bbase[NB_BUCKETS] = sm[t];
}

__global__ __launch_bounds__(256) void k_binscatter(const int* __restrict__ ei,
                                                    const u32* __restrict__ basep,
                                                    const u32* __restrict__ bbase,
                                                    uint2* __restrict__ pairs) {
    __shared__ u32 rk[NB_PAD];
    for (int i = threadIdx.x; i < NB_PAD; i += 256) rk[i] = 0;
    __syncthreads();
    int base = blockIdx.x * EPB;
    #pragma unroll 4
    for (int i = 0; i < EPB / 256; ++i) {
        int idx = base + i * 256 + threadIdx.x;
        if (idx < NNZ) {
            int s, d;
            if (idx < N_EDGES) { s = ei[idx]; d = ei[N_EDGES + idx]; }
            else { s = idx - N_EDGES; d = s; }
            int b = d >> 8;
            u32 r = atomicAdd(&rk[b], 1u);
            u32 pos = bbase[b] + basep[blockIdx.x * NB_PAD + b] + r;
            pairs[pos] = make_uint2((u32)s, (u32)d);
        }
    }
}

__global__ __launch_bounds__(256) void k_count2(const uint2* __restrict__ pairs,
                                                const u32* __restrict__ bbase,
                                                int* __restrict__ indeg) {
    __shared__ u32 c[256];
    c[threadIdx.x] = 0;
    __syncthreads();
    int b = blockIdx.x;
    int lo = bbase[b], hi = bbase[b + 1];
    for (int i = lo + threadIdx.x; i < hi; i += 256)
        atomicAdd(&c[pairs[i].y & 255], 1u);
    __syncthreads();
    int node = (b << 8) + threadIdx.x;
    if (node < N_NODES) indeg[node] = (int)c[threadIdx.x];
}

__global__ __launch_bounds__(256) void k_fill2(const uint2* __restrict__ pairs,
                                               const u32* __restrict__ bbase,
                                               const int* __restrict__ row_ptr,
                                               int* __restrict__ col_src) {
    __shared__ u32 c[256];
    c[threadIdx.x] = 0;
    __syncthreads();
    int b = blockIdx.x;
    int lo = bbase[b], hi = bbase[b + 1];
    for (int i = lo + threadIdx.x; i < hi; i += 256) {
        uint2 p = pairs[i];
        u32 r = atomicAdd(&c[p.y & 255], 1u);
        col_src[row_ptr[p.y] + r] = (int)p.x;
    }
}

// ---------------- hierarchical scan of indeg -> row_ptr (+ dinv) ----------------

__global__ __launch_bounds__(256) void k_scan_reduce(const int* __restrict__ indeg,
                                                     int* __restrict__ part) {
    int base = blockIdx.x * SCAN_BLK + threadIdx.x * 4;
    int s = 0;
    if (base < N_NODES) {
        int4 v = *(const int4*)(indeg + base);
        s = v.x + v.y + v.z + v.w;
    }
    for (int off = 32; off; off >>= 1) s += __shfl_xor(s, off);
    __shared__ int sm[4];
    if ((threadIdx.x & 63) == 0) sm[threadIdx.x >> 6] = s;
    __syncthreads();
    if (threadIdx.x == 0) part[blockIdx.x] = sm[0] + sm[1] + sm[2] + sm[3];
}

__global__ __launch_bounds__(128) void k_scan_top(const int* __restrict__ part,
                                                  int* __restrict__ poff,
                                                  int* __restrict__ row_ptr) {
    __shared__ int sm[128];
    int t = threadIdx.x;
    int v = (t < SCAN_NB) ? part[t] : 0;
    sm[t] = v;
    __syncthreads();
    for (int off = 1; off < 128; off <<= 1) {
        int u = (t >= off) ? sm[t - off] : 0;
        __syncthreads();
        sm[t] += u;
        __syncthreads();
    }
    if (t < SCAN_NB) poff[t] = sm[t] - v;
    if (t == 0) row_ptr[N_NODES] = NNZ;
}

__global__ __launch_bounds__(256) void k_scan_apply(const int* __restrict__ indeg,
                                                    const int* __restrict__ poff,
                                                    int* __restrict__ row_ptr,
                                                    float* __restrict__ dinv) {
    int t = threadIdx.x;
    int base = blockIdx.x * SCAN_BLK + t * 4;
    int4 v = {0, 0, 0, 0};
    if (base < N_NODES) v = *(const int4*)(indeg + base);
    int tot = v.x + v.y + v.z + v.w;
    __shared__ int sm[256];
    sm[t] = tot;
    __syncthreads();
    for (int off = 1; off < 256; off <<= 1) {
        int u = (t >= off) ? sm[t - off] : 0;
        __syncthreads();
        sm[t] += u;
        __syncthreads();
    }
    if (base >= N_NODES) return;
    int excl = sm[t] - tot + poff[blockIdx.x];
    int4 p = make_int4(excl, excl + v.x, excl + v.x + v.y, excl + v.x + v.y + v.z);
    *(int4*)(row_ptr + base) = p;
    float4 dv = make_float4(rsqrtf((float)v.x), rsqrtf((float)v.y),
                            rsqrtf((float)v.z), rsqrtf((float)v.w));
    *(float4*)(dinv + base) = dv;
}

// ---------------- fp32 -> bf16 convert ----------------

__global__ __launch_bounds__(256) void k_f2b(const float* __restrict__ in,
                                             u16* __restrict__ out, int n4) {
    int i = blockIdx.x * blockDim.x + threadIdx.x;
    if (i >= n4) return;
    float4 v = ((const float4*)in)[i];
    ushort4 o = { f2b(v.x), f2b(v.y), f2b(v.z), f2b(v.w) };
    ((ushort4*)out)[i] = o;
}

// ---------------- propagation (bf16 storage, fp32 accum), 128-dim ----------------
// 16-lane-group edge parallelism. Weight computed ONCE per edge in the chunk phase
// and staged through LDS (same-wave produce/consume, in-order LDS pipe) — the agg
// loop reads it with one broadcast ds_read instead of VMEM dinv load + mul.

__global__ __launch_bounds__(256) void k_prop_bf(const int* __restrict__ row_ptr,
                                                 const int* __restrict__ col_src,
                                                 const float* __restrict__ dinv,
                                                 const u16* __restrict__ hin,
                                                 u16* __restrict__ hout) {
    __shared__ float wbuf[4][64];
    int lane = threadIdx.x & 63;
    int wid  = threadIdx.x >> 6;
    int node = blockIdx.x * 4 + wid;
    if (node >= N_NODES) return;
    int j0 = row_ptr[node], j1 = row_ptr[node + 1];
    float dn = dinv[node];
    const int grp = lane >> 4;      // edge group 0..3
    const int dl  = lane & 15;      // dim slot: dims dl*8 .. dl*8+7
    f32x2 acc[4] = {};

    for (int base = j0; base < j1; base += 64) {
        int cnt = j1 - base; if (cnt > 64) cnt = 64;
        int jj = base + lane;
        int sidx = 0; float wv = 0.f;
        if (jj < j1) { sidx = col_src[jj]; wv = dinv[sidx] * dn; }
        wbuf[wid][lane] = wv;                      // stage weights (same-wave reuse)
        int l = 0;
        for (; l + 16 <= cnt; l += 16) {           // 16 edges: 4 gathers/lane in flight
            uint4 v[4]; f32x2 w2[4];
            #pragma unroll
            for (int q = 0; q < 4; ++q) {
                int e = l + q * 4 + grp;
                int s = __shfl(sidx, e);
                float wq = wbuf[wid][e];           // broadcast ds_read (LDS pipe)
                w2[q].x = wq; w2[q].y = wq;
                v[q] = *(const uint4*)(hin + (size_t)s * DIM + dl * 8);
            }
            #pragma unroll
            for (int q = 0; q < 4; ++q) {
                acc[0] = __builtin_elementwise_fma(bf2(v[q].x), w2[q], acc[0]);
                acc[1] = __builtin_elementwise_fma(bf2(v[q].y), w2[q], acc[1]);
                acc[2] = __builtin_elementwise_fma(bf2(v[q].z), w2[q], acc[2]);
                acc[3] = __builtin_elementwise_fma(bf2(v[q].w), w2[q], acc[3]);
            }
        }
        for (; l + 4 <= cnt; l += 4) {             // 4 edges per iteration
            int e = l + grp;
            int s = __shfl(sidx, e);
            float wq = wbuf[wid][e];
            f32x2 w2; w2.x = wq; w2.y = wq;
            uint4 v = *(const uint4*)(hin + (size_t)s * DIM + dl * 8);
            acc[0] = __builtin_elementwise_fma(bf2(v.x), w2, acc[0]);
            acc[1] = __builtin_elementwise_fma(bf2(v.y), w2, acc[1]);
            acc[2] = __builtin_elementwise_fma(bf2(v.z), w2, acc[2]);
            acc[3] = __builtin_elementwise_fma(bf2(v.w), w2, acc[3]);
        }
        for (; l < cnt; ++l) {                     // tail (<=3): group 0 only
            int s = __shfl(sidx, l);
            if (grp == 0) {
                float wq = wbuf[wid][l];
                f32x2 w2; w2.x = wq; w2.y = wq;
                uint4 v = *(const uint4*)(hin + (size_t)s * DIM + dl * 8);
                acc[0] = __builtin_elementwise_fma(bf2(v.x), w2, acc[0]);
                acc[1] = __builtin_elementwise_fma(bf2(v.y), w2, acc[1]);
                acc[2] = __builtin_elementwise_fma(bf2(v.z), w2, acc[2]);
                acc[3] = __builtin_elementwise_fma(bf2(v.w), w2, acc[3]);
            }
        }
    }
    #pragma unroll
    for (int d = 0; d < 4; ++d) {
        acc[d].x += __shfl_xor(acc[d].x, 16); acc[d].x += __shfl_xor(acc[d].x, 32);
        acc[d].y += __shfl_xor(acc[d].y, 16); acc[d].y += __shfl_xor(acc[d].y, 32);
    }
    if (grp == 0) {
        uint4 o;
        o.x = (u32)f2b(acc[0].x) | ((u32)f2b(acc[0].y) << 16);
        o.y = (u32)f2b(acc[1].x) | ((u32)f2b(acc[1].y) << 16);
        o.z = (u32)f2b(acc[2].x) | ((u32)f2b(acc[2].y) << 16);
        o.w = (u32)f2b(acc[3].x) | ((u32)f2b(acc[3].y) << 16);
        *(uint4*)(hout + (size_t)node * DIM + dl * 8) = o;
    }
}

// ---------------- MFMA GEMM: C[M][NT*16] = act(A[M][K] * W[NT*16][K]^T + b), bf16 out ----------------

template<int NT, bool BIAS, bool ACT>
__global__ __launch_bounds__(256) void k_gemm_mfma(const u16* __restrict__ A,
                                                   const u16* __restrict__ Wb,
                                                   const float* __restrict__ b,
                                                   u16* __restrict__ C,
                                                   int M, int K) {
    const int lane = threadIdx.x & 63;
    const int wave = threadIdx.x >> 6;
    const int m0 = blockIdx.x * 64 + wave * 16;
    const int row = lane & 15, kg = lane >> 4;
    const int Ntot = NT * 16;

    const u16* Ap = A + (size_t)(m0 + row) * K + kg * 8;
    f32x4 acc[NT] = {};

    for (int k0 = 0; k0 < K; k0 += 32) {
        bf16x8 a = *(const bf16x8*)(Ap + k0);
        #pragma unroll
        for (int nt = 0; nt < NT; ++nt) {
            const u16* Wp = Wb + (size_t)(nt * 16 + row) * K + k0 + kg * 8;
            bf16x8 bb = *(const bf16x8*)Wp;
            acc[nt] = __builtin_amdgcn_mfma_f32_16x16x32_bf16(a, bb, acc[nt], 0, 0, 0);
        }
    }

    #pragma unroll
    for (int nt = 0; nt < NT; ++nt) {
        float bias = BIAS ? b[nt * 16 + row] : 0.f;
        #pragma unroll
        for (int r = 0; r < 4; ++r) {
            float v = acc[nt][r] + bias;
            if (ACT) v = lrelu(v, 0.1f);
            int crow = m0 + kg * 4 + r;
            C[(size_t)crow * Ntot + nt * 16 + row] = f2b(v);
        }
    }
}

// ---------------- MFMA split-K GEMM (MLP L1): fp32 partials, row-guarded ----------------

template<int NT>
__global__ __launch_bounds__(256) void k_gemm_mfma_sk(const u16* __restrict__ A,
                                                      const u16* __restrict__ Wb,
                                                      float* __restrict__ C,
                                                      int M, int Ntot, int K, int kChunk) {
    const int lane = threadIdx.x & 63;
    const int wave = threadIdx.x >> 6;
    const int m0 = blockIdx.x * 64 + wave * 16;
    const int row = lane & 15, kg = lane >> 4;
    const int n0 = blockIdx.y * NT * 16;
    const int kBeg = blockIdx.z * kChunk;

    int arow = m0 + row; if (arow >= M) arow = M - 1;
    const u16* Ap = A + (size_t)arow * K + kg * 8;
    f32x4 acc[NT] = {};

    for (int k0 = kBeg; k0 < kBeg + kChunk; k0 += 32) {
        bf16x8 a = *(const bf16x8*)(Ap + k0);
        #pragma unroll
        for (int nt = 0; nt < NT; ++nt) {
            const u16* Wp = Wb + (size_t)(n0 + nt * 16 + row) * K + k0 + kg * 8;
            bf16x8 bb = *(const bf16x8*)Wp;
            acc[nt] = __builtin_amdgcn_mfma_f32_16x16x32_bf16(a, bb, acc[nt], 0, 0, 0);
        }
    }

    float* Cp = C + (size_t)blockIdx.z * M * Ntot;
    #pragma unroll
    for (int nt = 0; nt < NT; ++nt) {
        #pragma unroll
        for (int r = 0; r < 4; ++r) {
            int crow = m0 + kg * 4 + r;
            if (crow < M) Cp[(size_t)crow * Ntot + n0 + nt * 16 + row] = acc[nt][r];
        }
    }
}

// ---------------- GEMM fp32 (MLP tail) ----------------

template<int BM, int BN, int BK, int TM, int TN, bool BIAS, bool ACT>
__global__ __launch_bounds__(256) void k_gemm(const float* __restrict__ A,
                                              const float* __restrict__ W,
                                              const float* __restrict__ b,
                                              float* __restrict__ C,
                                              int M, int Ntot, int K) {
    __shared__ float As[BK][BM + 4];
    __shared__ float Bs[BK][BN + 4];
    const int t = threadIdx.x;
    const int m0 = blockIdx.x * BM, n0 = blockIdx.y * BN;
    const int ty = t / (BN / TN), tx = t % (BN / TN);

    float acc[TM][TN] = {};

    for (int k0 = 0; k0 < K; k0 += BK) {
        #pragma unroll
        for (int p = 0; p < BM * BK / 4 / 256; ++p) {
            int id = p * 256 + t;
            int m = id % BM, kk = (id / BM) * 4;
            float4 v = {0.f, 0.f, 0.f, 0.f};
            if (m0 + m < M) v = *(const float4*)(A + (size_t)(m0 + m) * K + k0 + kk);
            As[kk + 0][m] = v.x; As[kk + 1][m] = v.y;
            As[kk + 2][m] = v.z; As[kk + 3][m] = v.w;
        }
        #pragma unroll
        for (int p = 0; p < BN * BK / 4 / 256; ++p) {
            int id = p * 256 + t;
            int n = id % BN, kk = (id / BN) * 4;
            float4 v = *(const float4*)(W + (size_t)(n0 + n) * K + k0 + kk);
            Bs[kk + 0][n] = v.x; Bs[kk + 1][n] = v.y;
            Bs[kk + 2][n] = v.z; Bs[kk + 3][n] = v.w;
        }
        __syncthreads();

        #pragma unroll
        for (int k = 0; k < BK; ++k) {
            float a[TM], bb[TN];
            #pragma unroll
            for (int i = 0; i < TM; ++i) a[i] = As[k][ty * TM + i];
            #pragma unroll
            for (int j = 0; j < TN; ++j) bb[j] = Bs[k][tx * TN + j];
            #pragma unroll
            for (int i = 0; i < TM; ++i)
                #pragma unroll
                for (int j = 0; j < TN; ++j)
                    acc[i][j] += a[i] * bb[j];
        }
        __syncthreads();
    }

    #pragma unroll
    for (int i = 0; i < TM; ++i) {
        int row = m0 + ty * TM + i;
        if (row >= M) continue;
        float4 o;
        float* op = (float*)&o;
        #pragma unroll
        for (int j = 0; j < TN; ++j) {
            float r = acc[i][j];
            if (BIAS) r += b[n0 + tx * TN + j];
            if (ACT) r = lrelu(r, 0.1f);
            op[j] = r;
        }
        *(float4*)(C + (size_t)row * Ntot + n0 + tx * TN) = o;
    }
}

__global__ __launch_bounds__(256) void k_splitk_reduce(const float* __restrict__ part,
                                                       const float* __restrict__ b,
                                                       float* __restrict__ out) {
    const int total4 = NPOOL * L1DIM / 4;
    int idx = blockIdx.x * blockDim.x + threadIdx.x;
    if (idx >= total4) return;
    const size_t stride4 = (size_t)NPOOL * L1DIM / 4;
    const float4* p4 = (const float4*)part;
    float4 s = p4[idx];
    #pragma unroll
    for (int z = 1; z < SPLITK; ++z) {
        float4 v = p4[idx + z * stride4];
        s.x += v.x; s.y += v.y; s.z += v.z; s.w += v.w;
    }
    int col = (idx * 4) % L1DIM;
    float4 bb = *(const float4*)(b + col);
    s.x = lrelu(s.x + bb.x, 0.1f); s.y = lrelu(s.y + bb.y, 0.1f);
    s.z = lrelu(s.z + bb.z, 0.1f); s.w = lrelu(s.w + bb.w, 0.1f);
    ((float4*)out)[idx] = s;
}

// ---------------- tiny final linear ----------------

template<int KD, int OD, bool BIAS, bool ACT>
__global__ void k_linear(const float* __restrict__ in, const float* __restrict__ W,
                         const float* __restrict__ b, float* __restrict__ out, int nrows) {
    int idx = blockIdx.x * blockDim.x + threadIdx.x;
    int n = idx / OD, o = idx % OD;
    if (n >= nrows) return;
    const float4* ar = (const float4*)(in + (size_t)n * KD);
    const float4* wr = (const float4*)(W + (size_t)o * KD);
    float4 acc = {0.f, 0.f, 0.f, 0.f};
    #pragma unroll 8
    for (int k = 0; k < KD / 4; ++k) {
        float4 a = ar[k], w = wr[k];
        acc.x += a.x * w.x; acc.y += a.y * w.y;
        acc.z += a.z * w.z; acc.w += a.w * w.w;
    }
    float r = (acc.x + acc.y) + (acc.z + acc.w);
    if (BIAS) r += b[o];
    if (ACT) r = lrelu(r, 0.1f);
    out[idx] = r;
}

// ---------------- GAT scores ----------------

__global__ __launch_bounds__(256) void k_attn(const u16* __restrict__ g,
                                              const float* __restrict__ att_src,
                                              const float* __restrict__ att_dst,
                                              float* __restrict__ a_s, float* __restrict__ a_d) {
    int lane = threadIdx.x & 63;
    int node = blockIdx.x * 4 + (threadIdx.x >> 6);
    if (node >= N_NODES) return;
    float v = b2f(g[(size_t)node * HD3 + lane]);
    float s1 = v * att_src[lane];
    float s2 = v * att_dst[lane];
    for (int off = 32; off; off >>= 1) {
        s1 += __shfl_xor(s1, off);
        s2 += __shfl_xor(s2, off);
    }
    if (lane == 0) { a_s[node] = s1; a_d[node] = s2; }
}

// ---------------- GAT: online softmax + 16-lane-group aggregation, bf16 out ----------------
// per-edge exp weight computed once in the softmax phase, staged via LDS; agg loop
// reads it with one broadcast ds_read (no lrelu/exp/VMEM recompute on the VALU).

__global__ __launch_bounds__(256) void k_gat(const int* __restrict__ row_ptr,
                                             const int* __restrict__ col_src,
                                             const u16* __restrict__ g,
                                             const float* __restrict__ a_s,
                                             const float* __restrict__ a_d,
                                             const float* __restrict__ bg,
                                             u16* __restrict__ hout) {
    __shared__ float wbuf[4][64];
    int lane = threadIdx.x & 63;
    int wid  = threadIdx.x >> 6;
    int node = blockIdx.x * 4 + wid;
    if (node >= N_NODES) return;
    int j0 = row_ptr[node], j1 = row_ptr[node + 1];
    float ad = a_d[node];
    const int grp = lane >> 4, dl = lane & 15;   // dims dl*4 .. dl*4+3
    float m = -1e30f, den = 0.f;
    f32x2 acc[2] = {};

    for (int base = j0; base < j1; base += 64) {
        int cnt = j1 - base; if (cnt > 64) cnt = 64;
        int jj = base + lane;
        int sidx = 0;
        float e = -1e30f;
        if (jj < j1) { sidx = col_src[jj]; e = lrelu(a_s[sidx] + ad, 0.2f); }
        float cm = e;
        for (int off = 32; off; off >>= 1) cm = fmaxf(cm, __shfl_xor(cm, off));
        float nm = fmaxf(m, cm);
        float scale = __expf(m - nm);
        float wv = (jj < j1) ? __expf(e - nm) : 0.f;
        wbuf[wid][lane] = wv;                      // stage exp-weights (same-wave reuse)
        float cden = wv;
        for (int off = 32; off; off >>= 1) cden += __shfl_xor(cden, off);
        den = den * scale + cden;
        f32x2 sc2; sc2.x = scale; sc2.y = scale;
        acc[0] *= sc2; acc[1] *= sc2;
        m = nm;
        int l = 0;
        for (; l + 16 <= cnt; l += 16) {
            uint2 v[4]; f32x2 w2[4];
            #pragma unroll
            for (int q = 0; q < 4; ++q) {
                int e2 = l + q * 4 + grp;
                int s = __shfl(sidx, e2);
                float wq = wbuf[wid][e2];          // broadcast ds_read (LDS pipe)
                w2[q].x = wq; w2[q].y = wq;
                v[q] = *(const uint2*)(g + (size_t)s * HD3 + dl * 4);
            }
            #pragma unroll
            for (int q = 0; q < 4; ++q) {
                acc[0] = __builtin_elementwise_fma(bf2(v[q].x), w2[q], acc[0]);
                acc[1] = __builtin_elementwise_fma(bf2(v[q].y), w2[q], acc[1]);
            }
        }
        for (; l + 4 <= cnt; l += 4) {
            int e2 = l + grp;
            int s = __shfl(sidx, e2);
            float wq = wbuf[wid][e2];
            f32x2 w2; w2.x = wq; w2.y = wq;
            uint2 v = *(const uint2*)(g + (size_t)s * HD3 + dl * 4);
            acc[0] = __builtin_elementwise_fma(bf2(v.x), w2, acc[0]);
            acc[1] = __builtin_elementwise_fma(bf2(v.y), w2, acc[1]);
        }
        for (; l < cnt; ++l) {
            int s = __shfl(sidx, l);
            if (grp == 0) {
                float wq = wbuf[wid][l];
                f32x2 w2; w2.x = wq; w2.y = wq;
                uint2 v = *(const uint2*)(g + (size_t)s * HD3 + dl * 4);
                acc[0] = __builtin_elementwise_fma(bf2(v.x), w2, acc[0]);
                acc[1] = __builtin_elementwise_fma(bf2(v.y), w2, acc[1]);
            }
        }
    }
    #pragma unroll
    for (int d = 0; d < 2; ++d) {
        acc[d].x += __shfl_xor(acc[d].x, 16); acc[d].x += __shfl_xor(acc[d].x, 32);
        acc[d].y += __shfl_xor(acc[d].y, 16); acc[d].y += __shfl_xor(acc[d].y, 32);
    }
    if (grp == 0) {
        float r0 = lrelu(acc[0].x / den + bg[dl * 4 + 0], 0.1f);
        float r1 = lrelu(acc[0].y / den + bg[dl * 4 + 1], 0.1f);
        float r2 = lrelu(acc[1].x / den + bg[dl * 4 + 2], 0.1f);
        float r3 = lrelu(acc[1].y / den + bg[dl * 4 + 3], 0.1f);
        uint2 o;
        o.x = (u32)f2b(r0) | ((u32)f2b(r1) << 16);
        o.y = (u32)f2b(r2) | ((u32)f2b(r3) << 16);
        *(uint2*)(hout + (size_t)node * HD3 + dl * 4) = o;
    }
}

// ---------------- launch ----------------

extern "C" void kernel_launch(void* const* d_in, const int* in_sizes, int n_in,
                              void* d_out, int out_size, void* d_ws, size_t ws_size,
                              hipStream_t stream) {
    const float* x   = (const float*)d_in[0];
    const int*   ei  = (const int*)d_in[1];
    const float* W1  = (const float*)d_in[2];
    const float* b1  = (const float*)d_in[3];
    const float* W2  = (const float*)d_in[4];
    const float* b2  = (const float*)d_in[5];
    const float* Wg  = (const float*)d_in[6];
    const float* att_src = (const float*)d_in[7];
    const float* att_dst = (const float*)d_in[8];
    const float* bg  = (const float*)d_in[9];
    const float* L1  = (const float*)d_in[10];
    const float* bl1 = (const float*)d_in[11];
    const float* L2  = (const float*)d_in[12];
    const float* bl2 = (const float*)d_in[13];
    const float* L3  = (const float*)d_in[14];
    const float* bl3 = (const float*)d_in[15];
    float* out = (float*)d_out;

    char* w = (char*)d_ws;
    auto alloc = [&](size_t bytes) {
        char* p = w;
        w += (bytes + 255) & ~(size_t)255;
        return p;
    };
    int*   indeg    = (int*)alloc((size_t)N_NODES * 4);
    int*   row_ptr  = (int*)alloc((size_t)(N_NODES + 1) * 4);
    float* dinv     = (float*)alloc((size_t)N_NODES * 4);
    int*   col_src  = (int*)alloc((size_t)NNZ * 4);
    uint2* pairs    = (uint2*)alloc((size_t)NNZ * 8);
    u32*   cnt      = (u32*)alloc((size_t)NBLK * NB_PAD * 4);
    u32*   basep    = (u32*)alloc((size_t)NBLK * NB_PAD * 4);
    u32*   btot     = (u32*)alloc((size_t)NB_PAD * 4);
    u32*   bbase    = (u32*)alloc((size_t)(NB_BUCKETS + 1) * 4);
    u16*   bufX     = (u16*)alloc((size_t)N_NODES * DIM * 2);
    u16*   bufA     = (u16*)alloc((size_t)N_NODES * DIM * 2);
    u16*   bufB     = (u16*)alloc((size_t)N_NODES * DIM * 2);
    float* a_s      = (float*)alloc((size_t)N_NODES * 4);
    float* a_d      = (float*)alloc((size_t)N_NODES * 4);
    float* p1       = (float*)alloc((size_t)NPOOL * L1DIM * 4);
    float* p2       = (float*)alloc((size_t)NPOOL * L2DIM * 4);
    int*   part     = (int*)alloc((size_t)SCAN_NB * 4);
    int*   poff     = (int*)alloc((size_t)SCAN_NB * 4);
    u16*   W1b      = (u16*)alloc((size_t)DIM * DIM * 2);
    u16*   W2b      = (u16*)alloc((size_t)DIM * DIM * 2);
    u16*   Wgb      = (u16*)alloc((size_t)HD3 * DIM * 2);
    u16*   L1b      = (u16*)alloc((size_t)L1DIM * L1K * 2);
    u16*   gb    = bufX;            // aliases, lifetimes disjoint
    u16*   hGb   = bufA;            // GAT output, bf16 (2000 x 2560 row-major view)
    float* skbuf = (float*)bufB;    // split-K partials 16.4 MB

    dim3 b256(256);
    // CSR build
    k_hist<<<NBLK, b256, 0, stream>>>(ei, cnt);
    k_bscan_col<<<NB_BUCKETS, b256, 0, stream>>>(cnt, basep, btot);
    k_bscan_top<<<1, 512, 0, stream>>>(btot, bbase);
    k_binscatter<<<NBLK, b256, 0, stream>>>(ei, basep, bbase, pairs);
    k_count2<<<NB_BUCKETS, b256, 0, stream>>>(pairs, bbase, indeg);
    k_scan_reduce<<<SCAN_NB, b256, 0, stream>>>(indeg, part);
    k_scan_top<<<1, 128, 0, stream>>>(part, poff, row_ptr);
    k_scan_apply<<<SCAN_NB, b256, 0, stream>>>(indeg, poff, row_ptr, dinv);
    k_fill2<<<NB_BUCKETS, b256, 0, stream>>>(pairs, bbase, row_ptr, col_src);

    k_f2b<<<(N_NODES * DIM / 4 + 255) / 256, b256, 0, stream>>>(x, bufX, N_NODES * DIM / 4);
    k_f2b<<<(DIM * DIM / 4 + 255) / 256, b256, 0, stream>>>(W1, W1b, DIM * DIM / 4);
    k_f2b<<<(DIM * DIM / 4 + 255) / 256, b256, 0, stream>>>(W2, W2b, DIM * DIM / 4);
    k_f2b<<<(HD3 * DIM / 4 + 255) / 256, b256, 0, stream>>>(Wg, Wgb, HD3 * DIM / 4);
    k_f2b<<<(L1DIM * L1K / 4 + 255) / 256, b256, 0, stream>>>(L1, L1b, L1DIM * L1K / 4);

    int nb = (N_NODES + 3) / 4;
    int gemm_nb = N_NODES / 64;   // 1250
    // SGConv stage 1
    k_prop_bf<<<nb, b256, 0, stream>>>(row_ptr, col_src, dinv, bufX, bufA);
    k_prop_bf<<<nb, b256, 0, stream>>>(row_ptr, col_src, dinv, bufA, bufB);
    k_gemm_mfma<8, true, true><<<gemm_nb, b256, 0, stream>>>(bufB, W1b, b1, bufA, N_NODES, DIM);
    // SGConv stage 2
    k_prop_bf<<<nb, b256, 0, stream>>>(row_ptr, col_src, dinv, bufA, bufB);
    k_prop_bf<<<nb, b256, 0, stream>>>(row_ptr, col_src, dinv, bufB, bufA);
    k_gemm_mfma<8, true, true><<<gemm_nb, b256, 0, stream>>>(bufA, W2b, b2, bufB, N_NODES, DIM);
    // GAT projection: g = h @ Wg.T -> gb (bufX, N x 64 bf16)
    k_gemm_mfma<4, false, false><<<gemm_nb, b256, 0, stream>>>(bufB, Wgb, nullptr, gb, N_NODES, DIM);
    k_attn<<<nb, b256, 0, stream>>>(gb, att_src, att_dst, a_s, a_d);
    k_gat<<<nb, b256, 0, stream>>>(row_ptr, col_src, gb, a_s, a_d, bg, hGb);
    // pool(40) + MLP head: hGb viewed as (2000 x 2560) bf16; MFMA split-K -> fp32 partials
    k_gemm_mfma_sk<8><<<dim3(32, 4, SPLITK), b256, 0, stream>>>(
        hGb, L1b, skbuf, NPOOL, L1DIM, L1K, L1K / SPLITK);
    k_splitk_reduce<<<(NPOOL * L1DIM / 4 + 255) / 256, b256, 0, stream>>>(skbuf, bl1, p1);
    k_gemm<64, 64, 32, 4, 4, true, true><<<dim3(32, 4), b256, 0, stream>>>(p1, L2, bl2, p2, NPOOL, L2DIM, L1DIM);
    k_linear<256, 10, true, true><<<(NPOOL * 10 + 255) / 256, b256, 0, stream>>>(p2, L3, bl3, out, NPOOL);
}

// Round 16
// 491.479 us; speedup vs baseline: 1.0414x; 1.0414x over previous
//
#include <hip/hip_runtime.h>

#define N_NODES 80000
#define N_EDGES 1280000
#define NNZ (N_EDGES + N_NODES)
#define DIM 128
#define HD3 64
#define GROUP 40
#define NPOOL (N_NODES / GROUP)   // 2000
#define L1DIM 512
#define L2DIM 256
#define OUTD 10
#define SPLITK 4
#define L1K (HD3 * GROUP)          // 2560

#define SCAN_BLK 1024
#define SCAN_NB ((N_NODES + SCAN_BLK - 1) / SCAN_BLK)  // 79

// bucket sort for CSR build
#define NB_BUCKETS ((N_NODES + 255) >> 8)              // 313
#define NB_PAD 320
#define EPB 8192
#define NBLK ((NNZ + EPB - 1) / EPB)                   // 167

// merged f2b segment sizes (float4 quads)
#define QX  (N_NODES * DIM / 4)        // 2,560,000
#define QW1 (DIM * DIM / 4)            // 4096
#define QW2 (DIM * DIM / 4)            // 4096
#define QWG (HD3 * DIM / 4)            // 2048
#define QL1 (L1DIM * L1K / 4)          // 327,680
#define QTOT (QX + QW1 + QW2 + QWG + QL1)

typedef unsigned int u32;
typedef unsigned short u16;
typedef __bf16 bf16x8 __attribute__((ext_vector_type(8)));
typedef float f32x4 __attribute__((ext_vector_type(4)));
typedef float f32x2 __attribute__((ext_vector_type(2)));

__device__ __forceinline__ float lrelu(float v, float s) { return v > 0.f ? v : s * v; }

__device__ __forceinline__ float b2f(u16 b) {
    u32 u = ((u32)b) << 16;
    float f; __builtin_memcpy(&f, &u, 4); return f;
}
__device__ __forceinline__ u16 f2b(float f) {
    u32 u; __builtin_memcpy(&u, &f, 4);
    return (u16)((u + 0x7fffu + ((u >> 16) & 1u)) >> 16);
}
// unpack a bf16 pair (u32) into f32x2 {lo, hi}
__device__ __forceinline__ f32x2 bf2(u32 v) {
    f32x2 r;
    r.x = __uint_as_float(v << 16);
    r.y = __uint_as_float(v & 0xffff0000u);
    return r;
}

// ---------------- CSR build: two-level bucket sort (packed u32 pairs) ----------------
// pair encoding: bits [23:0] = src (< 2^17), bits [31:24] = dst & 255 (bucket-local)

__global__ __launch_bounds__(256) void k_hist(const int* __restrict__ ei, u32* __restrict__ cnt) {
    __shared__ u32 h[NB_PAD];
    for (int i = threadIdx.x; i < NB_PAD; i += 256) h[i] = 0;
    __syncthreads();
    int base = blockIdx.x * EPB;
    #pragma unroll 4
    for (int i = 0; i < EPB / 256; ++i) {
        int idx = base + i * 256 + threadIdx.x;
        if (idx < NNZ) {
            int d = (idx < N_EDGES) ? ei[N_EDGES + idx] : idx - N_EDGES;
            atomicAdd(&h[d >> 8], 1u);
        }
    }
    __syncthreads();
    for (int b = threadIdx.x; b < NB_BUCKETS; b += 256)
        cnt[blockIdx.x * NB_PAD + b] = h[b];
}

__global__ __launch_bounds__(256) void k_bscan_col(const u32* __restrict__ cnt,
                                                   u32* __restrict__ basep,
                                                   u32* __restrict__ btot) {
    int b = blockIdx.x, t = threadIdx.x;
    u32 v = (t < NBLK) ? cnt[t * NB_PAD + b] : 0;
    __shared__ u32 sm[256];
    sm[t] = v; __syncthreads();
    for (int off = 1; off < 256; off <<= 1) {
        u32 u = (t >= off) ? sm[t - off] : 0; __syncthreads();
        sm[t] += u; __syncthreads();
    }
    if (t < NBLK) basep[t * NB_PAD + b] = sm[t] - v;
    if (t == 255) btot[b] = sm[255];
}

__global__ __launch_bounds__(512) void k_bscan_top(const u32* __restrict__ btot,
                                                   u32* __restrict__ bbase) {
    __shared__ u32 sm[512];
    int t = threadIdx.x;
    u32 v = (t < NB_BUCKETS) ? btot[t] : 0;
    sm[t] = v; __syncthreads();
    for (int off = 1; off < 512; off <<= 1) {
        u32 u = (t >= off) ? sm[t - off] : 0; __syncthreads();
        sm[t] += u; __syncthreads();
    }
    if (t < NB_BUCKETS) bbase[t] = sm[t] - v;
    if (t == NB_BUCKETS - 1) bbase[NB_BUCKETS] = sm[t];
}

__global__ __launch_bounds__(256) void k_binscatter(const int* __restrict__ ei,
                                                    const u32* __restrict__ basep,
                                                    const u32* __restrict__ bbase,
                                                    u32* __restrict__ pairs) {
    __shared__ u32 rk[NB_PAD];
    for (int i = threadIdx.x; i < NB_PAD; i += 256) rk[i] = 0;
    __syncthreads();
    int base = blockIdx.x * EPB;
    #pragma unroll 4
    for (int i = 0; i < EPB / 256; ++i) {
        int idx = base + i * 256 + threadIdx.x;
        if (idx < NNZ) {
            int s, d;
            if (idx < N_EDGES) { s = ei[idx]; d = ei[N_EDGES + idx]; }
            else { s = idx - N_EDGES; d = s; }
            int b = d >> 8;
            u32 r = atomicAdd(&rk[b], 1u);
            u32 pos = bbase[b] + basep[blockIdx.x * NB_PAD + b] + r;
            pairs[pos] = ((u32)(d & 255) << 24) | (u32)s;
        }
    }
}

__global__ __launch_bounds__(256) void k_count2(const u32* __restrict__ pairs,
                                                const u32* __restrict__ bbase,
                                                int* __restrict__ indeg) {
    __shared__ u32 c[256];
    c[threadIdx.x] = 0;
    __syncthreads();
    int b = blockIdx.x;
    int lo = bbase[b], hi = bbase[b + 1];
    for (int i = lo + threadIdx.x; i < hi; i += 256)
        atomicAdd(&c[pairs[i] >> 24], 1u);
    __syncthreads();
    int node = (b << 8) + threadIdx.x;
    if (node < N_NODES) indeg[node] = (int)c[threadIdx.x];
}

__global__ __launch_bounds__(256) void k_fill2(const u32* __restrict__ pairs,
                                               const u32* __restrict__ bbase,
                                               const int* __restrict__ row_ptr,
                                               int* __restrict__ col_src) {
    __shared__ u32 c[256];
    c[threadIdx.x] = 0;
    __syncthreads();
    int b = blockIdx.x;
    int lo = bbase[b], hi = bbase[b + 1];
    for (int i = lo + threadIdx.x; i < hi; i += 256) {
        u32 p = pairs[i];
        u32 dl = p >> 24;
        int dst = (b << 8) + (int)dl;
        u32 r = atomicAdd(&c[dl], 1u);
        col_src[row_ptr[dst] + r] = (int)(p & 0xFFFFFFu);
    }
}

// ---------------- hierarchical scan of indeg -> row_ptr (+ dinv) ----------------

__global__ __launch_bounds__(256) void k_scan_reduce(const int* __restrict__ indeg,
                                                     int* __restrict__ part) {
    int base = blockIdx.x * SCAN_BLK + threadIdx.x * 4;
    int s = 0;
    if (base < N_NODES) {
        int4 v = *(const int4*)(indeg + base);
        s = v.x + v.y + v.z + v.w;
    }
    for (int off = 32; off; off >>= 1) s += __shfl_xor(s, off);
    __shared__ int sm[4];
    if ((threadIdx.x & 63) == 0) sm[threadIdx.x >> 6] = s;
    __syncthreads();
    if (threadIdx.x == 0) part[blockIdx.x] = sm[0] + sm[1] + sm[2] + sm[3];
}

__global__ __launch_bounds__(128) void k_scan_top(const int* __restrict__ part,
                                                  int* __restrict__ poff,
                                                  int* __restrict__ row_ptr) {
    __shared__ int sm[128];
    int t = threadIdx.x;
    int v = (t < SCAN_NB) ? part[t] : 0;
    sm[t] = v;
    __syncthreads();
    for (int off = 1; off < 128; off <<= 1) {
        int u = (t >= off) ? sm[t - off] : 0;
        __syncthreads();
        sm[t] += u;
        __syncthreads();
    }
    if (t < SCAN_NB) poff[t] = sm[t] - v;
    if (t == 0) row_ptr[N_NODES] = NNZ;
}

__global__ __launch_bounds__(256) void k_scan_apply(const int* __restrict__ indeg,
                                                    const int* __restrict__ poff,
                                                    int* __restrict__ row_ptr,
                                                    float* __restrict__ dinv) {
    int t = threadIdx.x;
    int base = blockIdx.x * SCAN_BLK + t * 4;
    int4 v = {0, 0, 0, 0};
    if (base < N_NODES) v = *(const int4*)(indeg + base);
    int tot = v.x + v.y + v.z + v.w;
    __shared__ int sm[256];
    sm[t] = tot;
    __syncthreads();
    for (int off = 1; off < 256; off <<= 1) {
        int u = (t >= off) ? sm[t - off] : 0;
        __syncthreads();
        sm[t] += u;
        __syncthreads();
    }
    if (base >= N_NODES) return;
    int excl = sm[t] - tot + poff[blockIdx.x];
    int4 p = make_int4(excl, excl + v.x, excl + v.x + v.y, excl + v.x + v.y + v.z);
    *(int4*)(row_ptr + base) = p;
    float4 dv = make_float4(rsqrtf((float)v.x), rsqrtf((float)v.y),
                            rsqrtf((float)v.z), rsqrtf((float)v.w));
    *(float4*)(dinv + base) = dv;
}

// ---------------- merged fp32 -> bf16 convert (5 segments, one launch) ----------------

__global__ __launch_bounds__(256) void k_f2b_all(const float* __restrict__ x,   u16* __restrict__ xb,
                                                 const float* __restrict__ w1,  u16* __restrict__ w1b,
                                                 const float* __restrict__ w2,  u16* __restrict__ w2b,
                                                 const float* __restrict__ wg,  u16* __restrict__ wgb,
                                                 const float* __restrict__ l1,  u16* __restrict__ l1b) {
    int i = blockIdx.x * blockDim.x + threadIdx.x;
    const float* src; u16* dst; int off;
    if (i < QX)                      { src = x;  dst = xb;  off = i; }
    else if (i < QX + QW1)           { src = w1; dst = w1b; off = i - QX; }
    else if (i < QX + QW1 + QW2)     { src = w2; dst = w2b; off = i - QX - QW1; }
    else if (i < QX + QW1 + QW2 + QWG) { src = wg; dst = wgb; off = i - QX - QW1 - QW2; }
    else if (i < QTOT)               { src = l1; dst = l1b; off = i - QX - QW1 - QW2 - QWG; }
    else return;
    float4 v = ((const float4*)src)[off];
    ushort4 o = { f2b(v.x), f2b(v.y), f2b(v.z), f2b(v.w) };
    ((ushort4*)dst)[off] = o;
}

// ---------------- propagation (bf16 storage, fp32 accum), 128-dim ----------------
// 16-lane-group edge parallelism; weight recomputed from L2-resident dinv (1 load +
// 1 mul) — measured faster than LDS staging for this cheap weight. Packed f32x2 FMA.

__global__ __launch_bounds__(256) void k_prop_bf(const int* __restrict__ row_ptr,
                                                 const int* __restrict__ col_src,
                                                 const float* __restrict__ dinv,
                                                 const u16* __restrict__ hin,
                                                 u16* __restrict__ hout) {
    int lane = threadIdx.x & 63;
    int node = blockIdx.x * 4 + (threadIdx.x >> 6);
    if (node >= N_NODES) return;
    int j0 = row_ptr[node], j1 = row_ptr[node + 1];
    float dn = dinv[node];
    const int grp = lane >> 4;      // edge group 0..3
    const int dl  = lane & 15;      // dim slot: dims dl*8 .. dl*8+7
    f32x2 acc[4] = {};

    for (int base = j0; base < j1; base += 64) {
        int cnt = j1 - base; if (cnt > 64) cnt = 64;
        int jj = base + lane;
        int sidx = (jj < j1) ? col_src[jj] : 0;
        int l = 0;
        for (; l + 16 <= cnt; l += 16) {           // 16 edges: 4 gathers/lane in flight
            uint4 v[4]; f32x2 w2[4];
            #pragma unroll
            for (int q = 0; q < 4; ++q) {
                int s = __shfl(sidx, l + q * 4 + grp);
                float wq = dinv[s] * dn;           // 16-lane broadcast load, L2-resident
                w2[q].x = wq; w2[q].y = wq;
                v[q] = *(const uint4*)(hin + (size_t)s * DIM + dl * 8);
            }
            #pragma unroll
            for (int q = 0; q < 4; ++q) {
                acc[0] = __builtin_elementwise_fma(bf2(v[q].x), w2[q], acc[0]);
                acc[1] = __builtin_elementwise_fma(bf2(v[q].y), w2[q], acc[1]);
                acc[2] = __builtin_elementwise_fma(bf2(v[q].z), w2[q], acc[2]);
                acc[3] = __builtin_elementwise_fma(bf2(v[q].w), w2[q], acc[3]);
            }
        }
        for (; l + 4 <= cnt; l += 4) {             // 4 edges per iteration
            int s = __shfl(sidx, l + grp);
            float wq = dinv[s] * dn;
            f32x2 w2; w2.x = wq; w2.y = wq;
            uint4 v = *(const uint4*)(hin + (size_t)s * DIM + dl * 8);
            acc[0] = __builtin_elementwise_fma(bf2(v.x), w2, acc[0]);
            acc[1] = __builtin_elementwise_fma(bf2(v.y), w2, acc[1]);
            acc[2] = __builtin_elementwise_fma(bf2(v.z), w2, acc[2]);
            acc[3] = __builtin_elementwise_fma(bf2(v.w), w2, acc[3]);
        }
        for (; l < cnt; ++l) {                     // tail (<=3): group 0 only
            int s = __shfl(sidx, l);
            if (grp == 0) {
                float wq = dinv[s] * dn;
                f32x2 w2; w2.x = wq; w2.y = wq;
                uint4 v = *(const uint4*)(hin + (size_t)s * DIM + dl * 8);
                acc[0] = __builtin_elementwise_fma(bf2(v.x), w2, acc[0]);
                acc[1] = __builtin_elementwise_fma(bf2(v.y), w2, acc[1]);
                acc[2] = __builtin_elementwise_fma(bf2(v.z), w2, acc[2]);
                acc[3] = __builtin_elementwise_fma(bf2(v.w), w2, acc[3]);
            }
        }
    }
    #pragma unroll
    for (int d = 0; d < 4; ++d) {
        acc[d].x += __shfl_xor(acc[d].x, 16); acc[d].x += __shfl_xor(acc[d].x, 32);
        acc[d].y += __shfl_xor(acc[d].y, 16); acc[d].y += __shfl_xor(acc[d].y, 32);
    }
    if (grp == 0) {
        uint4 o;
        o.x = (u32)f2b(acc[0].x) | ((u32)f2b(acc[0].y) << 16);
        o.y = (u32)f2b(acc[1].x) | ((u32)f2b(acc[1].y) << 16);
        o.z = (u32)f2b(acc[2].x) | ((u32)f2b(acc[2].y) << 16);
        o.w = (u32)f2b(acc[3].x) | ((u32)f2b(acc[3].y) << 16);
        *(uint4*)(hout + (size_t)node * DIM + dl * 8) = o;
    }
}

// ---------------- MFMA GEMM: C[M][NT*16] = act(A[M][K] * W[NT*16][K]^T + b), bf16 out ----------------

template<int NT, bool BIAS, bool ACT>
__global__ __launch_bounds__(256) void k_gemm_mfma(const u16* __restrict__ A,
                                                   const u16* __restrict__ Wb,
                                                   const float* __restrict__ b,
                                                   u16* __restrict__ C,
                                                   int M, int K) {
    const int lane = threadIdx.x & 63;
    const int wave = threadIdx.x >> 6;
    const int m0 = blockIdx.x * 64 + wave * 16;
    const int row = lane & 15, kg = lane >> 4;
    const int Ntot = NT * 16;

    const u16* Ap = A + (size_t)(m0 + row) * K + kg * 8;
    f32x4 acc[NT] = {};

    for (int k0 = 0; k0 < K; k0 += 32) {
        bf16x8 a = *(const bf16x8*)(Ap + k0);
        #pragma unroll
        for (int nt = 0; nt < NT; ++nt) {
            const u16* Wp = Wb + (size_t)(nt * 16 + row) * K + k0 + kg * 8;
            bf16x8 bb = *(const bf16x8*)Wp;
            acc[nt] = __builtin_amdgcn_mfma_f32_16x16x32_bf16(a, bb, acc[nt], 0, 0, 0);
        }
    }

    #pragma unroll
    for (int nt = 0; nt < NT; ++nt) {
        float bias = BIAS ? b[nt * 16 + row] : 0.f;
        #pragma unroll
        for (int r = 0; r < 4; ++r) {
            float v = acc[nt][r] + bias;
            if (ACT) v = lrelu(v, 0.1f);
            int crow = m0 + kg * 4 + r;
            C[(size_t)crow * Ntot + nt * 16 + row] = f2b(v);
        }
    }
}

// ---------------- MFMA split-K GEMM (MLP L1): fp32 partials, row-guarded ----------------

template<int NT>
__global__ __launch_bounds__(256) void k_gemm_mfma_sk(const u16* __restrict__ A,
                                                      const u16* __restrict__ Wb,
                                                      float* __restrict__ C,
                                                      int M, int Ntot, int K, int kChunk) {
    const int lane = threadIdx.x & 63;
    const int wave = threadIdx.x >> 6;
    const int m0 = blockIdx.x * 64 + wave * 16;
    const int row = lane & 15, kg = lane >> 4;
    const int n0 = blockIdx.y * NT * 16;
    const int kBeg = blockIdx.z * kChunk;

    int arow = m0 + row; if (arow >= M) arow = M - 1;
    const u16* Ap = A + (size_t)arow * K + kg * 8;
    f32x4 acc[NT] = {};

    for (int k0 = kBeg; k0 < kBeg + kChunk; k0 += 32) {
        bf16x8 a = *(const bf16x8*)(Ap + k0);
        #pragma unroll
        for (int nt = 0; nt < NT; ++nt) {
            const u16* Wp = Wb + (size_t)(n0 + nt * 16 + row) * K + k0 + kg * 8;
            bf16x8 bb = *(const bf16x8*)Wp;
            acc[nt] = __builtin_amdgcn_mfma_f32_16x16x32_bf16(a, bb, acc[nt], 0, 0, 0);
        }
    }

    float* Cp = C + (size_t)blockIdx.z * M * Ntot;
    #pragma unroll
    for (int nt = 0; nt < NT; ++nt) {
        #pragma unroll
        for (int r = 0; r < 4; ++r) {
            int crow = m0 + kg * 4 + r;
            if (crow < M) Cp[(size_t)crow * Ntot + n0 + nt * 16 + row] = acc[nt][r];
        }
    }
}

// ---------------- GEMM fp32 (MLP tail) ----------------

template<int BM, int BN, int BK, int TM, int TN, bool BIAS, bool ACT>
__global__ __launch_bounds__(256) void k_gemm(const float* __restrict__ A,
                                              const float* __restrict__ W,
                                              const float* __restrict__ b,
                                              float* __restrict__ C,
                                              int M, int Ntot, int K) {
    __shared__ float As[BK][BM + 4];
    __shared__ float Bs[BK][BN + 4];
    const int t = threadIdx.x;
    const int m0 = blockIdx.x * BM, n0 = blockIdx.y * BN;
    const int ty = t / (BN / TN), tx = t % (BN / TN);

    float acc[TM][TN] = {};

    for (int k0 = 0; k0 < K; k0 += BK) {
        #pragma unroll
        for (int p = 0; p < BM * BK / 4 / 256; ++p) {
            int id = p * 256 + t;
            int m = id % BM, kk = (id / BM) * 4;
            float4 v = {0.f, 0.f, 0.f, 0.f};
            if (m0 + m < M) v = *(const float4*)(A + (size_t)(m0 + m) * K + k0 + kk);
            As[kk + 0][m] = v.x; As[kk + 1][m] = v.y;
            As[kk + 2][m] = v.z; As[kk + 3][m] = v.w;
        }
        #pragma unroll
        for (int p = 0; p < BN * BK / 4 / 256; ++p) {
            int id = p * 256 + t;
            int n = id % BN, kk = (id / BN) * 4;
            float4 v = *(const float4*)(W + (size_t)(n0 + n) * K + k0 + kk);
            Bs[kk + 0][n] = v.x; Bs[kk + 1][n] = v.y;
            Bs[kk + 2][n] = v.z; Bs[kk + 3][n] = v.w;
        }
        __syncthreads();

        #pragma unroll
        for (int k = 0; k < BK; ++k) {
            float a[TM], bb[TN];
            #pragma unroll
            for (int i = 0; i < TM; ++i) a[i] = As[k][ty * TM + i];
            #pragma unroll
            for (int j = 0; j < TN; ++j) bb[j] = Bs[k][tx * TN + j];
            #pragma unroll
            for (int i = 0; i < TM; ++i)
                #pragma unroll
                for (int j = 0; j < TN; ++j)
                    acc[i][j] += a[i] * bb[j];
        }
        __syncthreads();
    }

    #pragma unroll
    for (int i = 0; i < TM; ++i) {
        int row = m0 + ty * TM + i;
        if (row >= M) continue;
        float4 o;
        float* op = (float*)&o;
        #pragma unroll
        for (int j = 0; j < TN; ++j) {
            float r = acc[i][j];
            if (BIAS) r += b[n0 + tx * TN + j];
            if (ACT) r = lrelu(r, 0.1f);
            op[j] = r;
        }
        *(float4*)(C + (size_t)row * Ntot + n0 + tx * TN) = o;
    }
}

__global__ __launch_bounds__(256) void k_splitk_reduce(const float* __restrict__ part,
                                                       const float* __restrict__ b,
                                                       float* __restrict__ out) {
    const int total4 = NPOOL * L1DIM / 4;
    int idx = blockIdx.x * blockDim.x + threadIdx.x;
    if (idx >= total4) return;
    const size_t stride4 = (size_t)NPOOL * L1DIM / 4;
    const float4* p4 = (const float4*)part;
    float4 s = p4[idx];
    #pragma unroll
    for (int z = 1; z < SPLITK; ++z) {
        float4 v = p4[idx + z * stride4];
        s.x += v.x; s.y += v.y; s.z += v.z; s.w += v.w;
    }
    int col = (idx * 4) % L1DIM;
    float4 bb = *(const float4*)(b + col);
    s.x = lrelu(s.x + bb.x, 0.1f); s.y = lrelu(s.y + bb.y, 0.1f);
    s.z = lrelu(s.z + bb.z, 0.1f); s.w = lrelu(s.w + bb.w, 0.1f);
    ((float4*)out)[idx] = s;
}

// ---------------- tiny final linear ----------------

template<int KD, int OD, bool BIAS, bool ACT>
__global__ void k_linear(const float* __restrict__ in, const float* __restrict__ W,
                         const float* __restrict__ b, float* __restrict__ out, int nrows) {
    int idx = blockIdx.x * blockDim.x + threadIdx.x;
    int n = idx / OD, o = idx % OD;
    if (n >= nrows) return;
    const float4* ar = (const float4*)(in + (size_t)n * KD);
    const float4* wr = (const float4*)(W + (size_t)o * KD);
    float4 acc = {0.f, 0.f, 0.f, 0.f};
    #pragma unroll 8
    for (int k = 0; k < KD / 4; ++k) {
        float4 a = ar[k], w = wr[k];
        acc.x += a.x * w.x; acc.y += a.y * w.y;
        acc.z += a.z * w.z; acc.w += a.w * w.w;
    }
    float r = (acc.x + acc.y) + (acc.z + acc.w);
    if (BIAS) r += b[o];
    if (ACT) r = lrelu(r, 0.1f);
    out[idx] = r;
}

// ---------------- GAT scores ----------------

__global__ __launch_bounds__(256) void k_attn(const u16* __restrict__ g,
                                              const float* __restrict__ att_src,
                                              const float* __restrict__ att_dst,
                                              float* __restrict__ a_s, float* __restrict__ a_d) {
    int lane = threadIdx.x & 63;
    int node = blockIdx.x * 4 + (threadIdx.x >> 6);
    if (node >= N_NODES) return;
    float v = b2f(g[(size_t)node * HD3 + lane]);
    float s1 = v * att_src[lane];
    float s2 = v * att_dst[lane];
    for (int off = 32; off; off >>= 1) {
        s1 += __shfl_xor(s1, off);
        s2 += __shfl_xor(s2, off);
    }
    if (lane == 0) { a_s[node] = s1; a_d[node] = s2; }
}

// ---------------- GAT: online softmax + 16-lane-group aggregation, bf16 out ----------------
// per-edge exp weight computed once in the softmax phase, staged via LDS (exp/lrelu
// recompute is expensive — LDS staging measured faster here, unlike prop).

__global__ __launch_bounds__(256) void k_gat(const int* __restrict__ row_ptr,
                                             const int* __restrict__ col_src,
                                             const u16* __restrict__ g,
                                             const float* __restrict__ a_s,
                                             const float* __restrict__ a_d,
                                             const float* __restrict__ bg,
                                             u16* __restrict__ hout) {
    __shared__ float wbuf[4][64];
    int lane = threadIdx.x & 63;
    int wid  = threadIdx.x >> 6;
    int node = blockIdx.x * 4 + wid;
    if (node >= N_NODES) return;
    int j0 = row_ptr[node], j1 = row_ptr[node + 1];
    float ad = a_d[node];
    const int grp = lane >> 4, dl = lane & 15;   // dims dl*4 .. dl*4+3
    float m = -1e30f, den = 0.f;
    f32x2 acc[2] = {};

    for (int base = j0; base < j1; base += 64) {
        int cnt = j1 - base; if (cnt > 64) cnt = 64;
        int jj = base + lane;
        int sidx = 0;
        float e = -1e30f;
        if (jj < j1) { sidx = col_src[jj]; e = lrelu(a_s[sidx] + ad, 0.2f); }
        float cm = e;
        for (int off = 32; off; off >>= 1) cm = fmaxf(cm, __shfl_xor(cm, off));
        float nm = fmaxf(m, cm);
        float scale = __expf(m - nm);
        float wv = (jj < j1) ? __expf(e - nm) : 0.f;
        wbuf[wid][lane] = wv;                      // stage exp-weights (same-wave reuse)
        float cden = wv;
        for (int off = 32; off; off >>= 1) cden += __shfl_xor(cden, off);
        den = den * scale + cden;
        f32x2 sc2; sc2.x = scale; sc2.y = scale;
        acc[0] *= sc2; acc[1] *= sc2;
        m = nm;
        int l = 0;
        for (; l + 16 <= cnt; l += 16) {
            uint2 v[4]; f32x2 w2[4];
            #pragma unroll
            for (int q = 0; q < 4; ++q) {
                int e2 = l + q * 4 + grp;
                int s = __shfl(sidx, e2);
                float wq = wbuf[wid][e2];          // broadcast ds_read (LDS pipe)
                w2[q].x = wq; w2[q].y = wq;
                v[q] = *(const uint2*)(g + (size_t)s * HD3 + dl * 4);
            }
            #pragma unroll
            for (int q = 0; q < 4; ++q) {
                acc[0] = __builtin_elementwise_fma(bf2(v[q].x), w2[q], acc[0]);
                acc[1] = __builtin_elementwise_fma(bf2(v[q].y), w2[q], acc[1]);
            }
        }
        for (; l + 4 <= cnt; l += 4) {
            int e2 = l + grp;
            int s = __shfl(sidx, e2);
            float wq = wbuf[wid][e2];
            f32x2 w2; w2.x = wq; w2.y = wq;
            uint2 v = *(const uint2*)(g + (size_t)s * HD3 + dl * 4);
            acc[0] = __builtin_elementwise_fma(bf2(v.x), w2, acc[0]);
            acc[1] = __builtin_elementwise_fma(bf2(v.y), w2, acc[1]);
        }
        for (; l < cnt; ++l) {
            int s = __shfl(sidx, l);
            if (grp == 0) {
                float wq = wbuf[wid][l];
                f32x2 w2; w2.x = wq; w2.y = wq;
                uint2 v = *(const uint2*)(g + (size_t)s * HD3 + dl * 4);
                acc[0] = __builtin_elementwise_fma(bf2(v.x), w2, acc[0]);
                acc[1] = __builtin_elementwise_fma(bf2(v.y), w2, acc[1]);
            }
        }
    }
    #pragma unroll
    for (int d = 0; d < 2; ++d) {
        acc[d].x += __shfl_xor(acc[d].x, 16); acc[d].x += __shfl_xor(acc[d].x, 32);
        acc[d].y += __shfl_xor(acc[d].y, 16); acc[d].y += __shfl_xor(acc[d].y, 32);
    }
    if (grp == 0) {
        float r0 = lrelu(acc[0].x / den + bg[dl * 4 + 0], 0.1f);
        float r1 = lrelu(acc[0].y / den + bg[dl * 4 + 1], 0.1f);
        float r2 = lrelu(acc[1].x / den + bg[dl * 4 + 2], 0.1f);
        float r3 = lrelu(acc[1].y / den + bg[dl * 4 + 3], 0.1f);
        uint2 o;
        o.x = (u32)f2b(r0) | ((u32)f2b(r1) << 16);
        o.y = (u32)f2b(r2) | ((u32)f2b(r3) << 16);
        *(uint2*)(hout + (size_t)node * HD3 + dl * 4) = o;
    }
}

// ---------------- launch ----------------

extern "C" void kernel_launch(void* const* d_in, const int* in_sizes, int n_in,
                              void* d_out, int out_size, void* d_ws, size_t ws_size,
                              hipStream_t stream) {
    const float* x   = (const float*)d_in[0];
    const int*   ei  = (const int*)d_in[1];
    const float* W1  = (const float*)d_in[2];
    const float* b1  = (const float*)d_in[3];
    const float* W2  = (const float*)d_in[4];
    const float* b2  = (const float*)d_in[5];
    const float* Wg  = (const float*)d_in[6];
    const float* att_src = (const float*)d_in[7];
    const float* att_dst = (const float*)d_in[8];
    const float* bg  = (const float*)d_in[9];
    const float* L1  = (const float*)d_in[10];
    const float* bl1 = (const float*)d_in[11];
    const float* L2  = (const float*)d_in[12];
    const float* bl2 = (const float*)d_in[13];
    const float* L3  = (const float*)d_in[14];
    const float* bl3 = (const float*)d_in[15];
    float* out = (float*)d_out;

    char* w = (char*)d_ws;
    auto alloc = [&](size_t bytes) {
        char* p = w;
        w += (bytes + 255) & ~(size_t)255;
        return p;
    };
    int*   indeg    = (int*)alloc((size_t)N_NODES * 4);
    int*   row_ptr  = (int*)alloc((size_t)(N_NODES + 1) * 4);
    float* dinv     = (float*)alloc((size_t)N_NODES * 4);
    int*   col_src  = (int*)alloc((size_t)NNZ * 4);
    u32*   pairs    = (u32*)alloc((size_t)NNZ * 4);
    u32*   cnt      = (u32*)alloc((size_t)NBLK * NB_PAD * 4);
    u32*   basep    = (u32*)alloc((size_t)NBLK * NB_PAD * 4);
    u32*   btot     = (u32*)alloc((size_t)NB_PAD * 4);
    u32*   bbase    = (u32*)alloc((size_t)(NB_BUCKETS + 1) * 4);
    u16*   bufX     = (u16*)alloc((size_t)N_NODES * DIM * 2);
    u16*   bufA     = (u16*)alloc((size_t)N_NODES * DIM * 2);
    u16*   bufB     = (u16*)alloc((size_t)N_NODES * DIM * 2);
    float* a_s      = (float*)alloc((size_t)N_NODES * 4);
    float* a_d      = (float*)alloc((size_t)N_NODES * 4);
    float* p1       = (float*)alloc((size_t)NPOOL * L1DIM * 4);
    float* p2       = (float*)alloc((size_t)NPOOL * L2DIM * 4);
    int*   part     = (int*)alloc((size_t)SCAN_NB * 4);
    int*   poff     = (int*)alloc((size_t)SCAN_NB * 4);
    u16*   W1b      = (u16*)alloc((size_t)DIM * DIM * 2);
    u16*   W2b      = (u16*)alloc((size_t)DIM * DIM * 2);
    u16*   Wgb      = (u16*)alloc((size_t)HD3 * DIM * 2);
    u16*   L1b      = (u16*)alloc((size_t)L1DIM * L1K * 2);
    u16*   gb    = bufX;            // aliases, lifetimes disjoint
    u16*   hGb   = bufA;            // GAT output, bf16 (2000 x 2560 row-major view)
    float* skbuf = (float*)bufB;    // split-K partials 16.4 MB

    dim3 b256(256);
    // CSR build
    k_hist<<<NBLK, b256, 0, stream>>>(ei, cnt);
    k_bscan_col<<<NB_BUCKETS, b256, 0, stream>>>(cnt, basep, btot);
    k_bscan_top<<<1, 512, 0, stream>>>(btot, bbase);
    k_binscatter<<<NBLK, b256, 0, stream>>>(ei, basep, bbase, pairs);
    k_count2<<<NB_BUCKETS, b256, 0, stream>>>(pairs, bbase, indeg);
    k_scan_reduce<<<SCAN_NB, b256, 0, stream>>>(indeg, part);
    k_scan_top<<<1, 128, 0, stream>>>(part, poff, row_ptr);
    k_scan_apply<<<SCAN_NB, b256, 0, stream>>>(indeg, poff, row_ptr, dinv);
    k_fill2<<<NB_BUCKETS, b256, 0, stream>>>(pairs, bbase, row_ptr, col_src);

    // all fp32->bf16 conversions in one launch
    k_f2b_all<<<(QTOT + 255) / 256, b256, 0, stream>>>(x, bufX, W1, W1b, W2, W2b, Wg, Wgb, L1, L1b);

    int nb = (N_NODES + 3) / 4;
    int gemm_nb = N_NODES / 64;   // 1250
    // SGConv stage 1
    k_prop_bf<<<nb, b256, 0, stream>>>(row_ptr, col_src, dinv, bufX, bufA);
    k_prop_bf<<<nb, b256, 0, stream>>>(row_ptr, col_src, dinv, bufA, bufB);
    k_gemm_mfma<8, true, true><<<gemm_nb, b256, 0, stream>>>(bufB, W1b, b1, bufA, N_NODES, DIM);
    // SGConv stage 2
    k_prop_bf<<<nb, b256, 0, stream>>>(row_ptr, col_src, dinv, bufA, bufB);
    k_prop_bf<<<nb, b256, 0, stream>>>(row_ptr, col_src, dinv, bufB, bufA);
    k_gemm_mfma<8, true, true><<<gemm_nb, b256, 0, stream>>>(bufA, W2b, b2, bufB, N_NODES, DIM);
    // GAT projection: g = h @ Wg.T -> gb (bufX, N x 64 bf16)
    k_gemm_mfma<4, false, false><<<gemm_nb, b256, 0, stream>>>(bufB, Wgb, nullptr, gb, N_NODES, DIM);
    k_attn<<<nb, b256, 0, stream>>>(gb, att_src, att_dst, a_s, a_d);
    k_gat<<<nb, b256, 0, stream>>>(row_ptr, col_src, gb, a_s, a_d, bg, hGb);
    // pool(40) + MLP head: hGb viewed as (2000 x 2560) bf16; MFMA split-K -> fp32 partials
    k_gemm_mfma_sk<8><<<dim3(32, 4, SPLITK), b256, 0, stream>>>(
        hGb, L1b, skbuf, NPOOL, L1DIM, L1K, L1K / SPLITK);
    k_splitk_reduce<<<(NPOOL * L1DIM / 4 + 255) / 256, b256, 0, stream>>>(skbuf, bl1, p1);
    k_gemm<64, 64, 32, 4, 4, true, true><<<dim3(32, 4), b256, 0, stream>>>(p1, L2, bl2, p2, NPOOL, L2DIM, L1DIM);
    k_linear<256, 10, true, true><<<(NPOOL * 10 + 255) / 256, b256, 0, stream>>>(p2, L3, bl3, out, NPOOL);
}

// Round 17
// 473.675 us; speedup vs baseline: 1.0805x; 1.0376x over previous
//
#include <hip/hip_runtime.h>

#define N_NODES 80000
#define N_EDGES 1280000
#define NNZ (N_EDGES + N_NODES)
#define DIM 128
#define HD3 64
#define GROUP 40
#define NPOOL (N_NODES / GROUP)   // 2000
#define L1DIM 512
#define L2DIM 256
#define OUTD 10
#define SPLITK 4
#define L1K (HD3 * GROUP)          // 2560

// bucket sort for CSR build
#define NB_BUCKETS ((N_NODES + 255) >> 8)              // 313
#define NB_PAD 320
#define EPB 8192
#define NBLK ((NNZ + EPB - 1) / EPB)                   // 167

// merged f2b segment sizes (float4 quads)
#define QX  (N_NODES * DIM / 4)
#define QW1 (DIM * DIM / 4)
#define QW2 (DIM * DIM / 4)
#define QWG (HD3 * DIM / 4)
#define QL1 (L1DIM * L1K / 4)
#define QTOT (QX + QW1 + QW2 + QWG + QL1)

typedef unsigned int u32;
typedef unsigned short u16;
typedef __bf16 bf16x8 __attribute__((ext_vector_type(8)));
typedef float f32x4 __attribute__((ext_vector_type(4)));
typedef float f32x2 __attribute__((ext_vector_type(2)));

__device__ __forceinline__ float lrelu(float v, float s) { return v > 0.f ? v : s * v; }

__device__ __forceinline__ float b2f(u16 b) {
    u32 u = ((u32)b) << 16;
    float f; __builtin_memcpy(&f, &u, 4); return f;
}
__device__ __forceinline__ u16 f2b(float f) {
    u32 u; __builtin_memcpy(&u, &f, 4);
    return (u16)((u + 0x7fffu + ((u >> 16) & 1u)) >> 16);
}
__device__ __forceinline__ f32x2 bf2(u32 v) {
    f32x2 r;
    r.x = __uint_as_float(v << 16);
    r.y = __uint_as_float(v & 0xffff0000u);
    return r;
}

// ---------------- CSR build: two-level bucket sort (packed u32 pairs) ----------------
// pair encoding: bits [23:0] = src (< 2^17), bits [31:24] = dst & 255 (bucket-local)

__global__ __launch_bounds__(256) void k_hist(const int* __restrict__ ei, u32* __restrict__ cnt) {
    __shared__ u32 h[NB_PAD];
    for (int i = threadIdx.x; i < NB_PAD; i += 256) h[i] = 0;
    __syncthreads();
    int base = blockIdx.x * EPB;
    #pragma unroll 4
    for (int i = 0; i < EPB / 256; ++i) {
        int idx = base + i * 256 + threadIdx.x;
        if (idx < NNZ) {
            int d = (idx < N_EDGES) ? ei[N_EDGES + idx] : idx - N_EDGES;
            atomicAdd(&h[d >> 8], 1u);
        }
    }
    __syncthreads();
    for (int b = threadIdx.x; b < NB_BUCKETS; b += 256)
        cnt[blockIdx.x * NB_PAD + b] = h[b];
}

__global__ __launch_bounds__(256) void k_bscan_col(const u32* __restrict__ cnt,
                                                   u32* __restrict__ basep,
                                                   u32* __restrict__ btot) {
    int b = blockIdx.x, t = threadIdx.x;
    u32 v = (t < NBLK) ? cnt[t * NB_PAD + b] : 0;
    __shared__ u32 sm[256];
    sm[t] = v; __syncthreads();
    for (int off = 1; off < 256; off <<= 1) {
        u32 u = (t >= off) ? sm[t - off] : 0; __syncthreads();
        sm[t] += u; __syncthreads();
    }
    if (t < NBLK) basep[t * NB_PAD + b] = sm[t] - v;
    if (t == 255) btot[b] = sm[255];
}

__global__ __launch_bounds__(512) void k_bscan_top(const u32* __restrict__ btot,
                                                   u32* __restrict__ bbase,
                                                   int* __restrict__ row_ptr) {
    __shared__ u32 sm[512];
    int t = threadIdx.x;
    u32 v = (t < NB_BUCKETS) ? btot[t] : 0;
    sm[t] = v; __syncthreads();
    for (int off = 1; off < 512; off <<= 1) {
        u32 u = (t >= off) ? sm[t - off] : 0; __syncthreads();
        sm[t] += u; __syncthreads();
    }
    if (t < NB_BUCKETS) bbase[t] = sm[t] - v;
    if (t == NB_BUCKETS - 1) bbase[NB_BUCKETS] = sm[t];
    if (t == 0) row_ptr[N_NODES] = NNZ;
}

__global__ __launch_bounds__(256) void k_binscatter(const int* __restrict__ ei,
                                                    const u32* __restrict__ basep,
                                                    const u32* __restrict__ bbase,
                                                    u32* __restrict__ pairs) {
    __shared__ u32 rk[NB_PAD];
    for (int i = threadIdx.x; i < NB_PAD; i += 256) rk[i] = 0;
    __syncthreads();
    int base = blockIdx.x * EPB;
    #pragma unroll 4
    for (int i = 0; i < EPB / 256; ++i) {
        int idx = base + i * 256 + threadIdx.x;
        if (idx < NNZ) {
            int s, d;
            if (idx < N_EDGES) { s = ei[idx]; d = ei[N_EDGES + idx]; }
            else { s = idx - N_EDGES; d = s; }
            int b = d >> 8;
            u32 r = atomicAdd(&rk[b], 1u);
            u32 pos = bbase[b] + basep[blockIdx.x * NB_PAD + b] + r;
            pairs[pos] = ((u32)(d & 255) << 24) | (u32)s;
        }
    }
}

// Fused CSR tail: per bucket — count (LDS) -> local excl scan -> row_ptr + dinv ->
// rank-scatter col_src. Valid because buckets are contiguous in node AND pair space:
// row_ptr[node] = bbase[b] + local_excl[node&255].
__global__ __launch_bounds__(256) void k_build_csr(const u32* __restrict__ pairs,
                                                   const u32* __restrict__ bbase,
                                                   int* __restrict__ row_ptr,
                                                   float* __restrict__ dinv,
                                                   int* __restrict__ col_src) {
    __shared__ u32 c[256], sc[256], ex[256];
    int t = threadIdx.x, b = blockIdx.x;
    int lo = bbase[b], hi = bbase[b + 1];
    c[t] = 0;
    __syncthreads();
    for (int i = lo + t; i < hi; i += 256)
        atomicAdd(&c[pairs[i] >> 24], 1u);
    __syncthreads();
    u32 cv = c[t];
    sc[t] = cv;
    __syncthreads();
    for (int off = 1; off < 256; off <<= 1) {
        u32 u = (t >= off) ? sc[t - off] : 0; __syncthreads();
        sc[t] += u; __syncthreads();
    }
    ex[t] = sc[t] - cv;
    int node = (b << 8) + t;
    if (node < N_NODES) {
        row_ptr[node] = lo + (int)ex[t];
        dinv[node] = rsqrtf((float)cv);     // deg >= 1 (self-loop)
    }
    c[t] = 0;
    __syncthreads();
    for (int i = lo + t; i < hi; i += 256) {
        u32 p = pairs[i];
        u32 dl = p >> 24;
        u32 r = atomicAdd(&c[dl], 1u);
        col_src[lo + (int)ex[dl] + (int)r] = (int)(p & 0xFFFFFFu);
    }
}

// ---------------- merged fp32 -> bf16 convert (5 segments, one launch) ----------------

__global__ __launch_bounds__(256) void k_f2b_all(const float* __restrict__ x,   u16* __restrict__ xb,
                                                 const float* __restrict__ w1,  u16* __restrict__ w1b,
                                                 const float* __restrict__ w2,  u16* __restrict__ w2b,
                                                 const float* __restrict__ wg,  u16* __restrict__ wgb,
                                                 const float* __restrict__ l1,  u16* __restrict__ l1b) {
    int i = blockIdx.x * blockDim.x + threadIdx.x;
    const float* src; u16* dst; int off;
    if (i < QX)                        { src = x;  dst = xb;  off = i; }
    else if (i < QX + QW1)             { src = w1; dst = w1b; off = i - QX; }
    else if (i < QX + QW1 + QW2)       { src = w2; dst = w2b; off = i - QX - QW1; }
    else if (i < QX + QW1 + QW2 + QWG) { src = wg; dst = wgb; off = i - QX - QW1 - QW2; }
    else if (i < QTOT)                 { src = l1; dst = l1b; off = i - QX - QW1 - QW2 - QWG; }
    else return;
    float4 v = ((const float4*)src)[off];
    ushort4 o = { f2b(v.x), f2b(v.y), f2b(v.z), f2b(v.w) };
    ((ushort4*)dst)[off] = o;
}

// ---------------- propagation (bf16 storage, fp32 accum), 128-dim ----------------

__global__ __launch_bounds__(256) void k_prop_bf(const int* __restrict__ row_ptr,
                                                 const int* __restrict__ col_src,
                                                 const float* __restrict__ dinv,
                                                 const u16* __restrict__ hin,
                                                 u16* __restrict__ hout) {
    int lane = threadIdx.x & 63;
    int node = blockIdx.x * 4 + (threadIdx.x >> 6);
    if (node >= N_NODES) return;
    int j0 = row_ptr[node], j1 = row_ptr[node + 1];
    float dn = dinv[node];
    const int grp = lane >> 4;      // edge group 0..3
    const int dl  = lane & 15;      // dim slot: dims dl*8 .. dl*8+7
    f32x2 acc[4] = {};

    for (int base = j0; base < j1; base += 64) {
        int cnt = j1 - base; if (cnt > 64) cnt = 64;
        int jj = base + lane;
        int sidx = (jj < j1) ? col_src[jj] : 0;
        int l = 0;
        for (; l + 16 <= cnt; l += 16) {
            uint4 v[4]; f32x2 w2[4];
            #pragma unroll
            for (int q = 0; q < 4; ++q) {
                int s = __shfl(sidx, l + q * 4 + grp);
                float wq = dinv[s] * dn;
                w2[q].x = wq; w2[q].y = wq;
                v[q] = *(const uint4*)(hin + (size_t)s * DIM + dl * 8);
            }
            #pragma unroll
            for (int q = 0; q < 4; ++q) {
                acc[0] = __builtin_elementwise_fma(bf2(v[q].x), w2[q], acc[0]);
                acc[1] = __builtin_elementwise_fma(bf2(v[q].y), w2[q], acc[1]);
                acc[2] = __builtin_elementwise_fma(bf2(v[q].z), w2[q], acc[2]);
                acc[3] = __builtin_elementwise_fma(bf2(v[q].w), w2[q], acc[3]);
            }
        }
        for (; l + 4 <= cnt; l += 4) {
            int s = __shfl(sidx, l + grp);
            float wq = dinv[s] * dn;
            f32x2 w2; w2.x = wq; w2.y = wq;
            uint4 v = *(const uint4*)(hin + (size_t)s * DIM + dl * 8);
            acc[0] = __builtin_elementwise_fma(bf2(v.x), w2, acc[0]);
            acc[1] = __builtin_elementwise_fma(bf2(v.y), w2, acc[1]);
            acc[2] = __builtin_elementwise_fma(bf2(v.z), w2, acc[2]);
            acc[3] = __builtin_elementwise_fma(bf2(v.w), w2, acc[3]);
        }
        for (; l < cnt; ++l) {
            int s = __shfl(sidx, l);
            if (grp == 0) {
                float wq = dinv[s] * dn;
                f32x2 w2; w2.x = wq; w2.y = wq;
                uint4 v = *(const uint4*)(hin + (size_t)s * DIM + dl * 8);
                acc[0] = __builtin_elementwise_fma(bf2(v.x), w2, acc[0]);
                acc[1] = __builtin_elementwise_fma(bf2(v.y), w2, acc[1]);
                acc[2] = __builtin_elementwise_fma(bf2(v.z), w2, acc[2]);
                acc[3] = __builtin_elementwise_fma(bf2(v.w), w2, acc[3]);
            }
        }
    }
    #pragma unroll
    for (int d = 0; d < 4; ++d) {
        acc[d].x += __shfl_xor(acc[d].x, 16); acc[d].x += __shfl_xor(acc[d].x, 32);
        acc[d].y += __shfl_xor(acc[d].y, 16); acc[d].y += __shfl_xor(acc[d].y, 32);
    }
    if (grp == 0) {
        uint4 o;
        o.x = (u32)f2b(acc[0].x) | ((u32)f2b(acc[0].y) << 16);
        o.y = (u32)f2b(acc[1].x) | ((u32)f2b(acc[1].y) << 16);
        o.z = (u32)f2b(acc[2].x) | ((u32)f2b(acc[2].y) << 16);
        o.w = (u32)f2b(acc[3].x) | ((u32)f2b(acc[3].y) << 16);
        *(uint4*)(hout + (size_t)node * DIM + dl * 8) = o;
    }
}

// ---------------- MFMA GEMM: C = act(A W^T + b), bf16 out; optional fused attn scores ----------------
// ATTN: a_s[row] = dot(C_row, att_src), a_d likewise — C row lives on 16 lanes x NT regs,
// partial dot per lane + 16-lane shfl_xor reduce (fp32, more accurate than bf16 re-read).

template<int NT, bool BIAS, bool ACT, bool ATTN>
__global__ __launch_bounds__(256) void k_gemm_mfma(const u16* __restrict__ A,
                                                   const u16* __restrict__ Wb,
                                                   const float* __restrict__ b,
                                                   u16* __restrict__ C,
                                                   const float* __restrict__ att_src,
                                                   const float* __restrict__ att_dst,
                                                   float* __restrict__ a_s,
                                                   float* __restrict__ a_d,
                                                   int M, int K) {
    const int lane = threadIdx.x & 63;
    const int wave = threadIdx.x >> 6;
    const int m0 = blockIdx.x * 64 + wave * 16;
    const int row = lane & 15, kg = lane >> 4;
    const int Ntot = NT * 16;

    const u16* Ap = A + (size_t)(m0 + row) * K + kg * 8;
    f32x4 acc[NT] = {};

    for (int k0 = 0; k0 < K; k0 += 32) {
        bf16x8 a = *(const bf16x8*)(Ap + k0);
        #pragma unroll
        for (int nt = 0; nt < NT; ++nt) {
            const u16* Wp = Wb + (size_t)(nt * 16 + row) * K + k0 + kg * 8;
            bf16x8 bb = *(const bf16x8*)Wp;
            acc[nt] = __builtin_amdgcn_mfma_f32_16x16x32_bf16(a, bb, acc[nt], 0, 0, 0);
        }
    }

    #pragma unroll
    for (int nt = 0; nt < NT; ++nt) {
        float bias = BIAS ? b[nt * 16 + row] : 0.f;
        #pragma unroll
        for (int r = 0; r < 4; ++r) {
            float v = acc[nt][r] + bias;
            if (ACT) v = lrelu(v, 0.1f);
            int crow = m0 + kg * 4 + r;
            C[(size_t)crow * Ntot + nt * 16 + row] = f2b(v);
        }
    }

    if (ATTN) {
        float s1[4] = {}, s2[4] = {};
        #pragma unroll
        for (int nt = 0; nt < NT; ++nt) {
            float as = att_src[nt * 16 + row];
            float av = att_dst[nt * 16 + row];
            #pragma unroll
            for (int r = 0; r < 4; ++r) {
                s1[r] += acc[nt][r] * as;
                s2[r] += acc[nt][r] * av;
            }
        }
        #pragma unroll
        for (int r = 0; r < 4; ++r) {
            #pragma unroll
            for (int off = 1; off < 16; off <<= 1) {
                s1[r] += __shfl_xor(s1[r], off);
                s2[r] += __shfl_xor(s2[r], off);
            }
        }
        if (row == 0) {
            #pragma unroll
            for (int r = 0; r < 4; ++r) {
                a_s[m0 + kg * 4 + r] = s1[r];
                a_d[m0 + kg * 4 + r] = s2[r];
            }
        }
    }
}

// ---------------- MFMA split-K GEMM (MLP L1) ----------------

template<int NT>
__global__ __launch_bounds__(256) void k_gemm_mfma_sk(const u16* __restrict__ A,
                                                      const u16* __restrict__ Wb,
                                                      float* __restrict__ C,
                                                      int M, int Ntot, int K, int kChunk) {
    const int lane = threadIdx.x & 63;
    const int wave = threadIdx.x >> 6;
    const int m0 = blockIdx.x * 64 + wave * 16;
    const int row = lane & 15, kg = lane >> 4;
    const int n0 = blockIdx.y * NT * 16;
    const int kBeg = blockIdx.z * kChunk;

    int arow = m0 + row; if (arow >= M) arow = M - 1;
    const u16* Ap = A + (size_t)arow * K + kg * 8;
    f32x4 acc[NT] = {};

    for (int k0 = kBeg; k0 < kBeg + kChunk; k0 += 32) {
        bf16x8 a = *(const bf16x8*)(Ap + k0);
        #pragma unroll
        for (int nt = 0; nt < NT; ++nt) {
            const u16* Wp = Wb + (size_t)(n0 + nt * 16 + row) * K + k0 + kg * 8;
            bf16x8 bb = *(const bf16x8*)Wp;
            acc[nt] = __builtin_amdgcn_mfma_f32_16x16x32_bf16(a, bb, acc[nt], 0, 0, 0);
        }
    }

    float* Cp = C + (size_t)blockIdx.z * M * Ntot;
    #pragma unroll
    for (int nt = 0; nt < NT; ++nt) {
        #pragma unroll
        for (int r = 0; r < 4; ++r) {
            int crow = m0 + kg * 4 + r;
            if (crow < M) Cp[(size_t)crow * Ntot + n0 + nt * 16 + row] = acc[nt][r];
        }
    }
}

// ---------------- GEMM fp32 (MLP tail) ----------------

template<int BM, int BN, int BK, int TM, int TN, bool BIAS, bool ACT>
__global__ __launch_bounds__(256) void k_gemm(const float* __restrict__ A,
                                              const float* __restrict__ W,
                                              const float* __restrict__ b,
                                              float* __restrict__ C,
                                              int M, int Ntot, int K) {
    __shared__ float As[BK][BM + 4];
    __shared__ float Bs[BK][BN + 4];
    const int t = threadIdx.x;
    const int m0 = blockIdx.x * BM, n0 = blockIdx.y * BN;
    const int ty = t / (BN / TN), tx = t % (BN / TN);

    float acc[TM][TN] = {};

    for (int k0 = 0; k0 < K; k0 += BK) {
        #pragma unroll
        for (int p = 0; p < BM * BK / 4 / 256; ++p) {
            int id = p * 256 + t;
            int m = id % BM, kk = (id / BM) * 4;
            float4 v = {0.f, 0.f, 0.f, 0.f};
            if (m0 + m < M) v = *(const float4*)(A + (size_t)(m0 + m) * K + k0 + kk);
            As[kk + 0][m] = v.x; As[kk + 1][m] = v.y;
            As[kk + 2][m] = v.z; As[kk + 3][m] = v.w;
        }
        #pragma unroll
        for (int p = 0; p < BN * BK / 4 / 256; ++p) {
            int id = p * 256 + t;
            int n = id % BN, kk = (id / BN) * 4;
            float4 v = *(const float4*)(W + (size_t)(n0 + n) * K + k0 + kk);
            Bs[kk + 0][n] = v.x; Bs[kk + 1][n] = v.y;
            Bs[kk + 2][n] = v.z; Bs[kk + 3][n] = v.w;
        }
        __syncthreads();

        #pragma unroll
        for (int k = 0; k < BK; ++k) {
            float a[TM], bb[TN];
            #pragma unroll
            for (int i = 0; i < TM; ++i) a[i] = As[k][ty * TM + i];
            #pragma unroll
            for (int j = 0; j < TN; ++j) bb[j] = Bs[k][tx * TN + j];
            #pragma unroll
            for (int i = 0; i < TM; ++i)
                #pragma unroll
                for (int j = 0; j < TN; ++j)
                    acc[i][j] += a[i] * bb[j];
        }
        __syncthreads();
    }

    #pragma unroll
    for (int i = 0; i < TM; ++i) {
        int row = m0 + ty * TM + i;
        if (row >= M) continue;
        float4 o;
        float* op = (float*)&o;
        #pragma unroll
        for (int j = 0; j < TN; ++j) {
            float r = acc[i][j];
            if (BIAS) r += b[n0 + tx * TN + j];
            if (ACT) r = lrelu(r, 0.1f);
            op[j] = r;
        }
        *(float4*)(C + (size_t)row * Ntot + n0 + tx * TN) = o;
    }
}

__global__ __launch_bounds__(256) void k_splitk_reduce(const float* __restrict__ part,
                                                       const float* __restrict__ b,
                                                       float* __restrict__ out) {
    const int total4 = NPOOL * L1DIM / 4;
    int idx = blockIdx.x * blockDim.x + threadIdx.x;
    if (idx >= total4) return;
    const size_t stride4 = (size_t)NPOOL * L1DIM / 4;
    const float4* p4 = (const float4*)part;
    float4 s = p4[idx];
    #pragma unroll
    for (int z = 1; z < SPLITK; ++z) {
        float4 v = p4[idx + z * stride4];
        s.x += v.x; s.y += v.y; s.z += v.z; s.w += v.w;
    }
    int col = (idx * 4) % L1DIM;
    float4 bb = *(const float4*)(b + col);
    s.x = lrelu(s.x + bb.x, 0.1f); s.y = lrelu(s.y + bb.y, 0.1f);
    s.z = lrelu(s.z + bb.z, 0.1f); s.w = lrelu(s.w + bb.w, 0.1f);
    ((float4*)out)[idx] = s;
}

// ---------------- tiny final linear ----------------

template<int KD, int OD, bool BIAS, bool ACT>
__global__ void k_linear(const float* __restrict__ in, const float* __restrict__ W,
                         const float* __restrict__ b, float* __restrict__ out, int nrows) {
    int idx = blockIdx.x * blockDim.x + threadIdx.x;
    int n = idx / OD, o = idx % OD;
    if (n >= nrows) return;
    const float4* ar = (const float4*)(in + (size_t)n * KD);
    const float4* wr = (const float4*)(W + (size_t)o * KD);
    float4 acc = {0.f, 0.f, 0.f, 0.f};
    #pragma unroll 8
    for (int k = 0; k < KD / 4; ++k) {
        float4 a = ar[k], w = wr[k];
        acc.x += a.x * w.x; acc.y += a.y * w.y;
        acc.z += a.z * w.z; acc.w += a.w * w.w;
    }
    float r = (acc.x + acc.y) + (acc.z + acc.w);
    if (BIAS) r += b[o];
    if (ACT) r = lrelu(r, 0.1f);
    out[idx] = r;
}

// ---------------- GAT: online softmax + 16-lane-group aggregation, bf16 out ----------------

__global__ __launch_bounds__(256) void k_gat(const int* __restrict__ row_ptr,
                                             const int* __restrict__ col_src,
                                             const u16* __restrict__ g,
                                             const float* __restrict__ a_s,
                                             const float* __restrict__ a_d,
                                             const float* __restrict__ bg,
                                             u16* __restrict__ hout) {
    __shared__ float wbuf[4][64];
    int lane = threadIdx.x & 63;
    int wid  = threadIdx.x >> 6;
    int node = blockIdx.x * 4 + wid;
    if (node >= N_NODES) return;
    int j0 = row_ptr[node], j1 = row_ptr[node + 1];
    float ad = a_d[node];
    const int grp = lane >> 4, dl = lane & 15;   // dims dl*4 .. dl*4+3
    float m = -1e30f, den = 0.f;
    f32x2 acc[2] = {};

    for (int base = j0; base < j1; base += 64) {
        int cnt = j1 - base; if (cnt > 64) cnt = 64;
        int jj = base + lane;
        int sidx = 0;
        float e = -1e30f;
        if (jj < j1) { sidx = col_src[jj]; e = lrelu(a_s[sidx] + ad, 0.2f); }
        float cm = e;
        for (int off = 32; off; off >>= 1) cm = fmaxf(cm, __shfl_xor(cm, off));
        float nm = fmaxf(m, cm);
        float scale = __expf(m - nm);
        float wv = (jj < j1) ? __expf(e - nm) : 0.f;
        wbuf[wid][lane] = wv;
        float cden = wv;
        for (int off = 32; off; off >>= 1) cden += __shfl_xor(cden, off);
        den = den * scale + cden;
        f32x2 sc2; sc2.x = scale; sc2.y = scale;
        acc[0] *= sc2; acc[1] *= sc2;
        m = nm;
        int l = 0;
        for (; l + 16 <= cnt; l += 16) {
            uint2 v[4]; f32x2 w2[4];
            #pragma unroll
            for (int q = 0; q < 4; ++q) {
                int e2 = l + q * 4 + grp;
                int s = __shfl(sidx, e2);
                float wq = wbuf[wid][e2];
                w2[q].x = wq; w2[q].y = wq;
                v[q] = *(const uint2*)(g + (size_t)s * HD3 + dl * 4);
            }
            #pragma unroll
            for (int q = 0; q < 4; ++q) {
                acc[0] = __builtin_elementwise_fma(bf2(v[q].x), w2[q], acc[0]);
                acc[1] = __builtin_elementwise_fma(bf2(v[q].y), w2[q], acc[1]);
            }
        }
        for (; l + 4 <= cnt; l += 4) {
            int e2 = l + grp;
            int s = __shfl(sidx, e2);
            float wq = wbuf[wid][e2];
            f32x2 w2; w2.x = wq; w2.y = wq;
            uint2 v = *(const uint2*)(g + (size_t)s * HD3 + dl * 4);
            acc[0] = __builtin_elementwise_fma(bf2(v.x), w2, acc[0]);
            acc[1] = __builtin_elementwise_fma(bf2(v.y), w2, acc[1]);
        }
        for (; l < cnt; ++l) {
            int s = __shfl(sidx, l);
            if (grp == 0) {
                float wq = wbuf[wid][l];
                f32x2 w2; w2.x = wq; w2.y = wq;
                uint2 v = *(const uint2*)(g + (size_t)s * HD3 + dl * 4);
                acc[0] = __builtin_elementwise_fma(bf2(v.x), w2, acc[0]);
                acc[1] = __builtin_elementwise_fma(bf2(v.y), w2, acc[1]);
            }
        }
    }
    #pragma unroll
    for (int d = 0; d < 2; ++d) {
        acc[d].x += __shfl_xor(acc[d].x, 16); acc[d].x += __shfl_xor(acc[d].x, 32);
        acc[d].y += __shfl_xor(acc[d].y, 16); acc[d].y += __shfl_xor(acc[d].y, 32);
    }
    if (grp == 0) {
        float r0 = lrelu(acc[0].x / den + bg[dl * 4 + 0], 0.1f);
        float r1 = lrelu(acc[0].y / den + bg[dl * 4 + 1], 0.1f);
        float r2 = lrelu(acc[1].x / den + bg[dl * 4 + 2], 0.1f);
        float r3 = lrelu(acc[1].y / den + bg[dl * 4 + 3], 0.1f);
        uint2 o;
        o.x = (u32)f2b(r0) | ((u32)f2b(r1) << 16);
        o.y = (u32)f2b(r2) | ((u32)f2b(r3) << 16);
        *(uint2*)(hout + (size_t)node * HD3 + dl * 4) = o;
    }
}

// ---------------- launch ----------------

extern "C" void kernel_launch(void* const* d_in, const int* in_sizes, int n_in,
                              void* d_out, int out_size, void* d_ws, size_t ws_size,
                              hipStream_t stream) {
    const float* x   = (const float*)d_in[0];
    const int*   ei  = (const int*)d_in[1];
    const float* W1  = (const float*)d_in[2];
    const float* b1  = (const float*)d_in[3];
    const float* W2  = (const float*)d_in[4];
    const float* b2  = (const float*)d_in[5];
    const float* Wg  = (const float*)d_in[6];
    const float* att_src = (const float*)d_in[7];
    const float* att_dst = (const float*)d_in[8];
    const float* bg  = (const float*)d_in[9];
    const float* L1  = (const float*)d_in[10];
    const float* bl1 = (const float*)d_in[11];
    const float* L2  = (const float*)d_in[12];
    const float* bl2 = (const float*)d_in[13];
    const float* L3  = (const float*)d_in[14];
    const float* bl3 = (const float*)d_in[15];
    float* out = (float*)d_out;

    char* w = (char*)d_ws;
    auto alloc = [&](size_t bytes) {
        char* p = w;
        w += (bytes + 255) & ~(size_t)255;
        return p;
    };
    int*   row_ptr  = (int*)alloc((size_t)(N_NODES + 1) * 4);
    float* dinv     = (float*)alloc((size_t)N_NODES * 4);
    int*   col_src  = (int*)alloc((size_t)NNZ * 4);
    u32*   pairs    = (u32*)alloc((size_t)NNZ * 4);
    u32*   cnt      = (u32*)alloc((size_t)NBLK * NB_PAD * 4);
    u32*   basep    = (u32*)alloc((size_t)NBLK * NB_PAD * 4);
    u32*   btot     = (u32*)alloc((size_t)NB_PAD * 4);
    u32*   bbase    = (u32*)alloc((size_t)(NB_BUCKETS + 1) * 4);
    u16*   bufX     = (u16*)alloc((size_t)N_NODES * DIM * 2);
    u16*   bufA     = (u16*)alloc((size_t)N_NODES * DIM * 2);
    u16*   bufB     = (u16*)alloc((size_t)N_NODES * DIM * 2);
    float* a_s      = (float*)alloc((size_t)N_NODES * 4);
    float* a_d      = (float*)alloc((size_t)N_NODES * 4);
    float* p1       = (float*)alloc((size_t)NPOOL * L1DIM * 4);
    float* p2       = (float*)alloc((size_t)NPOOL * L2DIM * 4);
    u16*   W1b      = (u16*)alloc((size_t)DIM * DIM * 2);
    u16*   W2b      = (u16*)alloc((size_t)DIM * DIM * 2);
    u16*   Wgb      = (u16*)alloc((size_t)HD3 * DIM * 2);
    u16*   L1b      = (u16*)alloc((size_t)L1DIM * L1K * 2);
    u16*   gb    = bufX;            // aliases, lifetimes disjoint
    u16*   hGb   = bufA;            // GAT output, bf16 (2000 x 2560 row-major view)
    float* skbuf = (float*)bufB;    // split-K partials 16.4 MB

    dim3 b256(256);
    // CSR build (5 kernels: hist, col-scan, top-scan, binscatter, fused build)
    k_hist<<<NBLK, b256, 0, stream>>>(ei, cnt);
    k_bscan_col<<<NB_BUCKETS, b256, 0, stream>>>(cnt, basep, btot);
    k_bscan_top<<<1, 512, 0, stream>>>(btot, bbase, row_ptr);
    k_binscatter<<<NBLK, b256, 0, stream>>>(ei, basep, bbase, pairs);
    k_build_csr<<<NB_BUCKETS, b256, 0, stream>>>(pairs, bbase, row_ptr, dinv, col_src);

    // all fp32->bf16 conversions in one launch
    k_f2b_all<<<(QTOT + 255) / 256, b256, 0, stream>>>(x, bufX, W1, W1b, W2, W2b, Wg, Wgb, L1, L1b);

    int nb = (N_NODES + 3) / 4;
    int gemm_nb = N_NODES / 64;   // 1250
    // SGConv stage 1
    k_prop_bf<<<nb, b256, 0, stream>>>(row_ptr, col_src, dinv, bufX, bufA);
    k_prop_bf<<<nb, b256, 0, stream>>>(row_ptr, col_src, dinv, bufA, bufB);
    k_gemm_mfma<8, true, true, false><<<gemm_nb, b256, 0, stream>>>(
        bufB, W1b, b1, bufA, nullptr, nullptr, nullptr, nullptr, N_NODES, DIM);
    // SGConv stage 2
    k_prop_bf<<<nb, b256, 0, stream>>>(row_ptr, col_src, dinv, bufA, bufB);
    k_prop_bf<<<nb, b256, 0, stream>>>(row_ptr, col_src, dinv, bufB, bufA);
    k_gemm_mfma<8, true, true, false><<<gemm_nb, b256, 0, stream>>>(
        bufA, W2b, b2, bufB, nullptr, nullptr, nullptr, nullptr, N_NODES, DIM);
    // GAT projection + fused attention scores: g -> gb, a_s/a_d from fp32 accumulators
    k_gemm_mfma<4, false, false, true><<<gemm_nb, b256, 0, stream>>>(
        bufB, Wgb, nullptr, gb, att_src, att_dst, a_s, a_d, N_NODES, DIM);
    k_gat<<<nb, b256, 0, stream>>>(row_ptr, col_src, gb, a_s, a_d, bg, hGb);
    // pool(40) + MLP head
    k_gemm_mfma_sk<8><<<dim3(32, 4, SPLITK), b256, 0, stream>>>(
        hGb, L1b, skbuf, NPOOL, L1DIM, L1K, L1K / SPLITK);
    k_splitk_reduce<<<(NPOOL * L1DIM / 4 + 255) / 256, b256, 0, stream>>>(skbuf, bl1, p1);
    k_gemm<64, 64, 32, 4, 4, true, true><<<dim3(32, 4), b256, 0, stream>>>(p1, L2, bl2, p2, NPOOL, L2DIM, L1DIM);
    k_linear<256, 10, true, true><<<(NPOOL * 10 + 255) / 256, b256, 0, stream>>>(p2, L3, bl3, out, NPOOL);
}

// Round 18
// 472.739 us; speedup vs baseline: 1.0827x; 1.0020x over previous
//
#include <hip/hip_runtime.h>

#define N_NODES 80000
#define N_EDGES 1280000
#define NNZ (N_EDGES + N_NODES)
#define DIM 128
#define HD3 64
#define GROUP 40
#define NPOOL (N_NODES / GROUP)   // 2000
#define L1DIM 512
#define L2DIM 256
#define OUTD 10
#define SPLITK 4
#define L1K (HD3 * GROUP)          // 2560

// bucket sort for CSR build
#define NB_BUCKETS ((N_NODES + 255) >> 8)              // 313
#define NB_PAD 320
#define EPB 8192
#define NBLK ((NNZ + EPB - 1) / EPB)                   // 167

// merged f2b segment sizes (float4 quads)
#define QX  (N_NODES * DIM / 4)
#define QW1 (DIM * DIM / 4)
#define QW2 (DIM * DIM / 4)
#define QWG (HD3 * DIM / 4)
#define QL1 (L1DIM * L1K / 4)
#define QTOT (QX + QW1 + QW2 + QWG + QL1)

typedef unsigned int u32;
typedef unsigned short u16;
typedef __bf16 bf16x8 __attribute__((ext_vector_type(8)));
typedef float f32x4 __attribute__((ext_vector_type(4)));
typedef float f32x2 __attribute__((ext_vector_type(2)));

__device__ __forceinline__ float lrelu(float v, float s) { return v > 0.f ? v : s * v; }

__device__ __forceinline__ float b2f(u16 b) {
    u32 u = ((u32)b) << 16;
    float f; __builtin_memcpy(&f, &u, 4); return f;
}
__device__ __forceinline__ u16 f2b(float f) {
    u32 u; __builtin_memcpy(&u, &f, 4);
    return (u16)((u + 0x7fffu + ((u >> 16) & 1u)) >> 16);
}
__device__ __forceinline__ f32x2 bf2(u32 v) {
    f32x2 r;
    r.x = __uint_as_float(v << 16);
    r.y = __uint_as_float(v & 0xffff0000u);
    return r;
}

// ---------------- CSR build: two-level bucket sort (packed u32 pairs) ----------------
// pair encoding: bits [23:0] = src (< 2^17), bits [31:24] = dst & 255 (bucket-local)

__global__ __launch_bounds__(256) void k_hist(const int* __restrict__ ei, u32* __restrict__ cnt) {
    __shared__ u32 h[NB_PAD];
    for (int i = threadIdx.x; i < NB_PAD; i += 256) h[i] = 0;
    __syncthreads();
    int base = blockIdx.x * EPB;
    #pragma unroll 4
    for (int i = 0; i < EPB / 256; ++i) {
        int idx = base + i * 256 + threadIdx.x;
        if (idx < NNZ) {
            int d = (idx < N_EDGES) ? ei[N_EDGES + idx] : idx - N_EDGES;
            atomicAdd(&h[d >> 8], 1u);
        }
    }
    __syncthreads();
    for (int b = threadIdx.x; b < NB_BUCKETS; b += 256)
        cnt[blockIdx.x * NB_PAD + b] = h[b];
}

__global__ __launch_bounds__(256) void k_bscan_col(const u32* __restrict__ cnt,
                                                   u32* __restrict__ basep,
                                                   u32* __restrict__ btot) {
    int b = blockIdx.x, t = threadIdx.x;
    u32 v = (t < NBLK) ? cnt[t * NB_PAD + b] : 0;
    __shared__ u32 sm[256];
    sm[t] = v; __syncthreads();
    for (int off = 1; off < 256; off <<= 1) {
        u32 u = (t >= off) ? sm[t - off] : 0; __syncthreads();
        sm[t] += u; __syncthreads();
    }
    if (t < NBLK) basep[t * NB_PAD + b] = sm[t] - v;
    if (t == 255) btot[b] = sm[255];
}

__global__ __launch_bounds__(512) void k_bscan_top(const u32* __restrict__ btot,
                                                   u32* __restrict__ bbase,
                                                   int* __restrict__ row_ptr) {
    __shared__ u32 sm[512];
    int t = threadIdx.x;
    u32 v = (t < NB_BUCKETS) ? btot[t] : 0;
    sm[t] = v; __syncthreads();
    for (int off = 1; off < 512; off <<= 1) {
        u32 u = (t >= off) ? sm[t - off] : 0; __syncthreads();
        sm[t] += u; __syncthreads();
    }
    if (t < NB_BUCKETS) bbase[t] = sm[t] - v;
    if (t == NB_BUCKETS - 1) bbase[NB_BUCKETS] = sm[t];
    if (t == 0) row_ptr[N_NODES] = NNZ;
}

__global__ __launch_bounds__(256) void k_binscatter(const int* __restrict__ ei,
                                                    const u32* __restrict__ basep,
                                                    const u32* __restrict__ bbase,
                                                    u32* __restrict__ pairs) {
    __shared__ u32 rk[NB_PAD];
    for (int i = threadIdx.x; i < NB_PAD; i += 256) rk[i] = 0;
    __syncthreads();
    int base = blockIdx.x * EPB;
    #pragma unroll 4
    for (int i = 0; i < EPB / 256; ++i) {
        int idx = base + i * 256 + threadIdx.x;
        if (idx < NNZ) {
            int s, d;
            if (idx < N_EDGES) { s = ei[idx]; d = ei[N_EDGES + idx]; }
            else { s = idx - N_EDGES; d = s; }
            int b = d >> 8;
            u32 r = atomicAdd(&rk[b], 1u);
            u32 pos = bbase[b] + basep[blockIdx.x * NB_PAD + b] + r;
            pairs[pos] = ((u32)(d & 255) << 24) | (u32)s;
        }
    }
}

// Fused CSR tail: per bucket — count (LDS) -> local excl scan -> row_ptr + dinv ->
// rank-scatter col_src. Valid because buckets are contiguous in node AND pair space:
// row_ptr[node] = bbase[b] + local_excl[node&255].
__global__ __launch_bounds__(256) void k_build_csr(const u32* __restrict__ pairs,
                                                   const u32* __restrict__ bbase,
                                                   int* __restrict__ row_ptr,
                                                   float* __restrict__ dinv,
                                                   int* __restrict__ col_src) {
    __shared__ u32 c[256], sc[256], ex[256];
    int t = threadIdx.x, b = blockIdx.x;
    int lo = bbase[b], hi = bbase[b + 1];
    c[t] = 0;
    __syncthreads();
    for (int i = lo + t; i < hi; i += 256)
        atomicAdd(&c[pairs[i] >> 24], 1u);
    __syncthreads();
    u32 cv = c[t];
    sc[t] = cv;
    __syncthreads();
    for (int off = 1; off < 256; off <<= 1) {
        u32 u = (t >= off) ? sc[t - off] : 0; __syncthreads();
        sc[t] += u; __syncthreads();
    }
    ex[t] = sc[t] - cv;
    int node = (b << 8) + t;
    if (node < N_NODES) {
        row_ptr[node] = lo + (int)ex[t];
        dinv[node] = rsqrtf((float)cv);     // deg >= 1 (self-loop)
    }
    c[t] = 0;
    __syncthreads();
    for (int i = lo + t; i < hi; i += 256) {
        u32 p = pairs[i];
        u32 dl = p >> 24;
        u32 r = atomicAdd(&c[dl], 1u);
        col_src[lo + (int)ex[dl] + (int)r] = (int)(p & 0xFFFFFFu);
    }
}

// ---------------- merged fp32 -> bf16 convert (5 segments, one launch) ----------------

__global__ __launch_bounds__(256) void k_f2b_all(const float* __restrict__ x,   u16* __restrict__ xb,
                                                 const float* __restrict__ w1,  u16* __restrict__ w1b,
                                                 const float* __restrict__ w2,  u16* __restrict__ w2b,
                                                 const float* __restrict__ wg,  u16* __restrict__ wgb,
                                                 const float* __restrict__ l1,  u16* __restrict__ l1b) {
    int i = blockIdx.x * blockDim.x + threadIdx.x;
    const float* src; u16* dst; int off;
    if (i < QX)                        { src = x;  dst = xb;  off = i; }
    else if (i < QX + QW1)             { src = w1; dst = w1b; off = i - QX; }
    else if (i < QX + QW1 + QW2)       { src = w2; dst = w2b; off = i - QX - QW1; }
    else if (i < QX + QW1 + QW2 + QWG) { src = wg; dst = wgb; off = i - QX - QW1 - QW2; }
    else if (i < QTOT)                 { src = l1; dst = l1b; off = i - QX - QW1 - QW2 - QWG; }
    else return;
    float4 v = ((const float4*)src)[off];
    ushort4 o = { f2b(v.x), f2b(v.y), f2b(v.z), f2b(v.w) };
    ((ushort4*)dst)[off] = o;
}

// ---------------- propagation (bf16 storage, fp32 accum), 128-dim ----------------

__global__ __launch_bounds__(256) void k_prop_bf(const int* __restrict__ row_ptr,
                                                 const int* __restrict__ col_src,
                                                 const float* __restrict__ dinv,
                                                 const u16* __restrict__ hin,
                                                 u16* __restrict__ hout) {
    int lane = threadIdx.x & 63;
    int node = blockIdx.x * 4 + (threadIdx.x >> 6);
    if (node >= N_NODES) return;
    int j0 = row_ptr[node], j1 = row_ptr[node + 1];
    float dn = dinv[node];
    const int grp = lane >> 4;      // edge group 0..3
    const int dl  = lane & 15;      // dim slot: dims dl*8 .. dl*8+7
    f32x2 acc[4] = {};

    for (int base = j0; base < j1; base += 64) {
        int cnt = j1 - base; if (cnt > 64) cnt = 64;
        int jj = base + lane;
        int sidx = (jj < j1) ? col_src[jj] : 0;
        int l = 0;
        for (; l + 16 <= cnt; l += 16) {
            uint4 v[4]; f32x2 w2[4];
            #pragma unroll
            for (int q = 0; q < 4; ++q) {
                int s = __shfl(sidx, l + q * 4 + grp);
                float wq = dinv[s] * dn;
                w2[q].x = wq; w2[q].y = wq;
                v[q] = *(const uint4*)(hin + (size_t)s * DIM + dl * 8);
            }
            #pragma unroll
            for (int q = 0; q < 4; ++q) {
                acc[0] = __builtin_elementwise_fma(bf2(v[q].x), w2[q], acc[0]);
                acc[1] = __builtin_elementwise_fma(bf2(v[q].y), w2[q], acc[1]);
                acc[2] = __builtin_elementwise_fma(bf2(v[q].z), w2[q], acc[2]);
                acc[3] = __builtin_elementwise_fma(bf2(v[q].w), w2[q], acc[3]);
            }
        }
        for (; l + 4 <= cnt; l += 4) {
            int s = __shfl(sidx, l + grp);
            float wq = dinv[s] * dn;
            f32x2 w2; w2.x = wq; w2.y = wq;
            uint4 v = *(const uint4*)(hin + (size_t)s * DIM + dl * 8);
            acc[0] = __builtin_elementwise_fma(bf2(v.x), w2, acc[0]);
            acc[1] = __builtin_elementwise_fma(bf2(v.y), w2, acc[1]);
            acc[2] = __builtin_elementwise_fma(bf2(v.z), w2, acc[2]);
            acc[3] = __builtin_elementwise_fma(bf2(v.w), w2, acc[3]);
        }
        for (; l < cnt; ++l) {
            int s = __shfl(sidx, l);
            if (grp == 0) {
                float wq = dinv[s] * dn;
                f32x2 w2; w2.x = wq; w2.y = wq;
                uint4 v = *(const uint4*)(hin + (size_t)s * DIM + dl * 8);
                acc[0] = __builtin_elementwise_fma(bf2(v.x), w2, acc[0]);
                acc[1] = __builtin_elementwise_fma(bf2(v.y), w2, acc[1]);
                acc[2] = __builtin_elementwise_fma(bf2(v.z), w2, acc[2]);
                acc[3] = __builtin_elementwise_fma(bf2(v.w), w2, acc[3]);
            }
        }
    }
    #pragma unroll
    for (int d = 0; d < 4; ++d) {
        acc[d].x += __shfl_xor(acc[d].x, 16); acc[d].x += __shfl_xor(acc[d].x, 32);
        acc[d].y += __shfl_xor(acc[d].y, 16); acc[d].y += __shfl_xor(acc[d].y, 32);
    }
    if (grp == 0) {
        uint4 o;
        o.x = (u32)f2b(acc[0].x) | ((u32)f2b(acc[0].y) << 16);
        o.y = (u32)f2b(acc[1].x) | ((u32)f2b(acc[1].y) << 16);
        o.z = (u32)f2b(acc[2].x) | ((u32)f2b(acc[2].y) << 16);
        o.w = (u32)f2b(acc[3].x) | ((u32)f2b(acc[3].y) << 16);
        *(uint4*)(hout + (size_t)node * DIM + dl * 8) = o;
    }
}

// ---------------- MFMA GEMM: C = act(A W^T + b), bf16 out; optional fused attn scores ----------------
// ATTN: a_s[row] = dot(C_row, att_src), a_d likewise — C row lives on 16 lanes x NT regs,
// partial dot per lane + 16-lane shfl_xor reduce (fp32, more accurate than bf16 re-read).

template<int NT, bool BIAS, bool ACT, bool ATTN>
__global__ __launch_bounds__(256) void k_gemm_mfma(const u16* __restrict__ A,
                                                   const u16* __restrict__ Wb,
                                                   const float* __restrict__ b,
                                                   u16* __restrict__ C,
                                                   const float* __restrict__ att_src,
                                                   const float* __restrict__ att_dst,
                                                   float* __restrict__ a_s,
                                                   float* __restrict__ a_d,
                                                   int M, int K) {
    const int lane = threadIdx.x & 63;
    const int wave = threadIdx.x >> 6;
    const int m0 = blockIdx.x * 64 + wave * 16;
    const int row = lane & 15, kg = lane >> 4;
    const int Ntot = NT * 16;

    const u16* Ap = A + (size_t)(m0 + row) * K + kg * 8;
    f32x4 acc[NT] = {};

    for (int k0 = 0; k0 < K; k0 += 32) {
        bf16x8 a = *(const bf16x8*)(Ap + k0);
        #pragma unroll
        for (int nt = 0; nt < NT; ++nt) {
            const u16* Wp = Wb + (size_t)(nt * 16 + row) * K + k0 + kg * 8;
            bf16x8 bb = *(const bf16x8*)Wp;
            acc[nt] = __builtin_amdgcn_mfma_f32_16x16x32_bf16(a, bb, acc[nt], 0, 0, 0);
        }
    }

    #pragma unroll
    for (int nt = 0; nt < NT; ++nt) {
        float bias = BIAS ? b[nt * 16 + row] : 0.f;
        #pragma unroll
        for (int r = 0; r < 4; ++r) {
            float v = acc[nt][r] + bias;
            if (ACT) v = lrelu(v, 0.1f);
            int crow = m0 + kg * 4 + r;
            C[(size_t)crow * Ntot + nt * 16 + row] = f2b(v);
        }
    }

    if (ATTN) {
        float s1[4] = {}, s2[4] = {};
        #pragma unroll
        for (int nt = 0; nt < NT; ++nt) {
            float as = att_src[nt * 16 + row];
            float av = att_dst[nt * 16 + row];
            #pragma unroll
            for (int r = 0; r < 4; ++r) {
                s1[r] += acc[nt][r] * as;
                s2[r] += acc[nt][r] * av;
            }
        }
        #pragma unroll
        for (int r = 0; r < 4; ++r) {
            #pragma unroll
            for (int off = 1; off < 16; off <<= 1) {
                s1[r] += __shfl_xor(s1[r], off);
                s2[r] += __shfl_xor(s2[r], off);
            }
        }
        if (row == 0) {
            #pragma unroll
            for (int r = 0; r < 4; ++r) {
                a_s[m0 + kg * 4 + r] = s1[r];
                a_d[m0 + kg * 4 + r] = s2[r];
            }
        }
    }
}

// ---------------- MFMA split-K GEMM (MLP L1) ----------------

template<int NT>
__global__ __launch_bounds__(256) void k_gemm_mfma_sk(const u16* __restrict__ A,
                                                      const u16* __restrict__ Wb,
                                                      float* __restrict__ C,
                                                      int M, int Ntot, int K, int kChunk) {
    const int lane = threadIdx.x & 63;
    const int wave = threadIdx.x >> 6;
    const int m0 = blockIdx.x * 64 + wave * 16;
    const int row = lane & 15, kg = lane >> 4;
    const int n0 = blockIdx.y * NT * 16;
    const int kBeg = blockIdx.z * kChunk;

    int arow = m0 + row; if (arow >= M) arow = M - 1;
    const u16* Ap = A + (size_t)arow * K + kg * 8;
    f32x4 acc[NT] = {};

    for (int k0 = kBeg; k0 < kBeg + kChunk; k0 += 32) {
        bf16x8 a = *(const bf16x8*)(Ap + k0);
        #pragma unroll
        for (int nt = 0; nt < NT; ++nt) {
            const u16* Wp = Wb + (size_t)(n0 + nt * 16 + row) * K + k0 + kg * 8;
            bf16x8 bb = *(const bf16x8*)Wp;
            acc[nt] = __builtin_amdgcn_mfma_f32_16x16x32_bf16(a, bb, acc[nt], 0, 0, 0);
        }
    }

    float* Cp = C + (size_t)blockIdx.z * M * Ntot;
    #pragma unroll
    for (int nt = 0; nt < NT; ++nt) {
        #pragma unroll
        for (int r = 0; r < 4; ++r) {
            int crow = m0 + kg * 4 + r;
            if (crow < M) Cp[(size_t)crow * Ntot + n0 + nt * 16 + row] = acc[nt][r];
        }
    }
}

// ---------------- GEMM fp32 (MLP tail) ----------------

template<int BM, int BN, int BK, int TM, int TN, bool BIAS, bool ACT>
__global__ __launch_bounds__(256) void k_gemm(const float* __restrict__ A,
                                              const float* __restrict__ W,
                                              const float* __restrict__ b,
                                              float* __restrict__ C,
                                              int M, int Ntot, int K) {
    __shared__ float As[BK][BM + 4];
    __shared__ float Bs[BK][BN + 4];
    const int t = threadIdx.x;
    const int m0 = blockIdx.x * BM, n0 = blockIdx.y * BN;
    const int ty = t / (BN / TN), tx = t % (BN / TN);

    float acc[TM][TN] = {};

    for (int k0 = 0; k0 < K; k0 += BK) {
        #pragma unroll
        for (int p = 0; p < BM * BK / 4 / 256; ++p) {
            int id = p * 256 + t;
            int m = id % BM, kk = (id / BM) * 4;
            float4 v = {0.f, 0.f, 0.f, 0.f};
            if (m0 + m < M) v = *(const float4*)(A + (size_t)(m0 + m) * K + k0 + kk);
            As[kk + 0][m] = v.x; As[kk + 1][m] = v.y;
            As[kk + 2][m] = v.z; As[kk + 3][m] = v.w;
        }
        #pragma unroll
        for (int p = 0; p < BN * BK / 4 / 256; ++p) {
            int id = p * 256 + t;
            int n = id % BN, kk = (id / BN) * 4;
            float4 v = *(const float4*)(W + (size_t)(n0 + n) * K + k0 + kk);
            Bs[kk + 0][n] = v.x; Bs[kk + 1][n] = v.y;
            Bs[kk + 2][n] = v.z; Bs[kk + 3][n] = v.w;
        }
        __syncthreads();

        #pragma unroll
        for (int k = 0; k < BK; ++k) {
            float a[TM], bb[TN];
            #pragma unroll
            for (int i = 0; i < TM; ++i) a[i] = As[k][ty * TM + i];
            #pragma unroll
            for (int j = 0; j < TN; ++j) bb[j] = Bs[k][tx * TN + j];
            #pragma unroll
            for (int i = 0; i < TM; ++i)
                #pragma unroll
                for (int j = 0; j < TN; ++j)
                    acc[i][j] += a[i] * bb[j];
        }
        __syncthreads();
    }

    #pragma unroll
    for (int i = 0; i < TM; ++i) {
        int row = m0 + ty * TM + i;
        if (row >= M) continue;
        float4 o;
        float* op = (float*)&o;
        #pragma unroll
        for (int j = 0; j < TN; ++j) {
            float r = acc[i][j];
            if (BIAS) r += b[n0 + tx * TN + j];
            if (ACT) r = lrelu(r, 0.1f);
            op[j] = r;
        }
        *(float4*)(C + (size_t)row * Ntot + n0 + tx * TN) = o;
    }
}

__global__ __launch_bounds__(256) void k_splitk_reduce(const float* __restrict__ part,
                                                       const float* __restrict__ b,
                                                       float* __restrict__ out) {
    const int total4 = NPOOL * L1DIM / 4;
    int idx = blockIdx.x * blockDim.x + threadIdx.x;
    if (idx >= total4) return;
    const size_t stride4 = (size_t)NPOOL * L1DIM / 4;
    const float4* p4 = (const float4*)part;
    float4 s = p4[idx];
    #pragma unroll
    for (int z = 1; z < SPLITK; ++z) {
        float4 v = p4[idx + z * stride4];
        s.x += v.x; s.y += v.y; s.z += v.z; s.w += v.w;
    }
    int col = (idx * 4) % L1DIM;
    float4 bb = *(const float4*)(b + col);
    s.x = lrelu(s.x + bb.x, 0.1f); s.y = lrelu(s.y + bb.y, 0.1f);
    s.z = lrelu(s.z + bb.z, 0.1f); s.w = lrelu(s.w + bb.w, 0.1f);
    ((float4*)out)[idx] = s;
}

// ---------------- tiny final linear ----------------

template<int KD, int OD, bool BIAS, bool ACT>
__global__ void k_linear(const float* __restrict__ in, const float* __restrict__ W,
                         const float* __restrict__ b, float* __restrict__ out, int nrows) {
    int idx = blockIdx.x * blockDim.x + threadIdx.x;
    int n = idx / OD, o = idx % OD;
    if (n >= nrows) return;
    const float4* ar = (const float4*)(in + (size_t)n * KD);
    const float4* wr = (const float4*)(W + (size_t)o * KD);
    float4 acc = {0.f, 0.f, 0.f, 0.f};
    #pragma unroll 8
    for (int k = 0; k < KD / 4; ++k) {
        float4 a = ar[k], w = wr[k];
        acc.x += a.x * w.x; acc.y += a.y * w.y;
        acc.z += a.z * w.z; acc.w += a.w * w.w;
    }
    float r = (acc.x + acc.y) + (acc.z + acc.w);
    if (BIAS) r += b[o];
    if (ACT) r = lrelu(r, 0.1f);
    out[idx] = r;
}

// ---------------- GAT: online softmax + 16-lane-group aggregation, bf16 out ----------------

__global__ __launch_bounds__(256) void k_gat(const int* __restrict__ row_ptr,
                                             const int* __restrict__ col_src,
                                             const u16* __restrict__ g,
                                             const float* __restrict__ a_s,
                                             const float* __restrict__ a_d,
                                             const float* __restrict__ bg,
                                             u16* __restrict__ hout) {
    __shared__ float wbuf[4][64];
    int lane = threadIdx.x & 63;
    int wid  = threadIdx.x >> 6;
    int node = blockIdx.x * 4 + wid;
    if (node >= N_NODES) return;
    int j0 = row_ptr[node], j1 = row_ptr[node + 1];
    float ad = a_d[node];
    const int grp = lane >> 4, dl = lane & 15;   // dims dl*4 .. dl*4+3
    float m = -1e30f, den = 0.f;
    f32x2 acc[2] = {};

    for (int base = j0; base < j1; base += 64) {
        int cnt = j1 - base; if (cnt > 64) cnt = 64;
        int jj = base + lane;
        int sidx = 0;
        float e = -1e30f;
        if (jj < j1) { sidx = col_src[jj]; e = lrelu(a_s[sidx] + ad, 0.2f); }
        float cm = e;
        for (int off = 32; off; off >>= 1) cm = fmaxf(cm, __shfl_xor(cm, off));
        float nm = fmaxf(m, cm);
        float scale = __expf(m - nm);
        float wv = (jj < j1) ? __expf(e - nm) : 0.f;
        wbuf[wid][lane] = wv;
        float cden = wv;
        for (int off = 32; off; off >>= 1) cden += __shfl_xor(cden, off);
        den = den * scale + cden;
        f32x2 sc2; sc2.x = scale; sc2.y = scale;
        acc[0] *= sc2; acc[1] *= sc2;
        m = nm;
        int l = 0;
        for (; l + 16 <= cnt; l += 16) {
            uint2 v[4]; f32x2 w2[4];
            #pragma unroll
            for (int q = 0; q < 4; ++q) {
                int e2 = l + q * 4 + grp;
                int s = __shfl(sidx, e2);
                float wq = wbuf[wid][e2];
                w2[q].x = wq; w2[q].y = wq;
                v[q] = *(const uint2*)(g + (size_t)s * HD3 + dl * 4);
            }
            #pragma unroll
            for (int q = 0; q < 4; ++q) {
                acc[0] = __builtin_elementwise_fma(bf2(v[q].x), w2[q], acc[0]);
                acc[1] = __builtin_elementwise_fma(bf2(v[q].y), w2[q], acc[1]);
            }
        }
        for (; l + 4 <= cnt; l += 4) {
            int e2 = l + grp;
            int s = __shfl(sidx, e2);
            float wq = wbuf[wid][e2];
            f32x2 w2; w2.x = wq; w2.y = wq;
            uint2 v = *(const uint2*)(g + (size_t)s * HD3 + dl * 4);
            acc[0] = __builtin_elementwise_fma(bf2(v.x), w2, acc[0]);
            acc[1] = __builtin_elementwise_fma(bf2(v.y), w2, acc[1]);
        }
        for (; l < cnt; ++l) {
            int s = __shfl(sidx, l);
            if (grp == 0) {
                float wq = wbuf[wid][l];
                f32x2 w2; w2.x = wq; w2.y = wq;
                uint2 v = *(const uint2*)(g + (size_t)s * HD3 + dl * 4);
                acc[0] = __builtin_elementwise_fma(bf2(v.x), w2, acc[0]);
                acc[1] = __builtin_elementwise_fma(bf2(v.y), w2, acc[1]);
            }
        }
    }
    #pragma unroll
    for (int d = 0; d < 2; ++d) {
        acc[d].x += __shfl_xor(acc[d].x, 16); acc[d].x += __shfl_xor(acc[d].x, 32);
        acc[d].y += __shfl_xor(acc[d].y, 16); acc[d].y += __shfl_xor(acc[d].y, 32);
    }
    if (grp == 0) {
        float r0 = lrelu(acc[0].x / den + bg[dl * 4 + 0], 0.1f);
        float r1 = lrelu(acc[0].y / den + bg[dl * 4 + 1], 0.1f);
        float r2 = lrelu(acc[1].x / den + bg[dl * 4 + 2], 0.1f);
        float r3 = lrelu(acc[1].y / den + bg[dl * 4 + 3], 0.1f);
        uint2 o;
        o.x = (u32)f2b(r0) | ((u32)f2b(r1) << 16);
        o.y = (u32)f2b(r2) | ((u32)f2b(r3) << 16);
        *(uint2*)(hout + (size_t)node * HD3 + dl * 4) = o;
    }
}

// ---------------- launch ----------------

extern "C" void kernel_launch(void* const* d_in, const int* in_sizes, int n_in,
                              void* d_out, int out_size, void* d_ws, size_t ws_size,
                              hipStream_t stream) {
    const float* x   = (const float*)d_in[0];
    const int*   ei  = (const int*)d_in[1];
    const float* W1  = (const float*)d_in[2];
    const float* b1  = (const float*)d_in[3];
    const float* W2  = (const float*)d_in[4];
    const float* b2  = (const float*)d_in[5];
    const float* Wg  = (const float*)d_in[6];
    const float* att_src = (const float*)d_in[7];
    const float* att_dst = (const float*)d_in[8];
    const float* bg  = (const float*)d_in[9];
    const float* L1  = (const float*)d_in[10];
    const float* bl1 = (const float*)d_in[11];
    const float* L2  = (const float*)d_in[12];
    const float* bl2 = (const float*)d_in[13];
    const float* L3  = (const float*)d_in[14];
    const float* bl3 = (const float*)d_in[15];
    float* out = (float*)d_out;

    char* w = (char*)d_ws;
    auto alloc = [&](size_t bytes) {
        char* p = w;
        w += (bytes + 255) & ~(size_t)255;
        return p;
    };
    int*   row_ptr  = (int*)alloc((size_t)(N_NODES + 1) * 4);
    float* dinv     = (float*)alloc((size_t)N_NODES * 4);
    int*   col_src  = (int*)alloc((size_t)NNZ * 4);
    u32*   pairs    = (u32*)alloc((size_t)NNZ * 4);
    u32*   cnt      = (u32*)alloc((size_t)NBLK * NB_PAD * 4);
    u32*   basep    = (u32*)alloc((size_t)NBLK * NB_PAD * 4);
    u32*   btot     = (u32*)alloc((size_t)NB_PAD * 4);
    u32*   bbase    = (u32*)alloc((size_t)(NB_BUCKETS + 1) * 4);
    u16*   bufX     = (u16*)alloc((size_t)N_NODES * DIM * 2);
    u16*   bufA     = (u16*)alloc((size_t)N_NODES * DIM * 2);
    u16*   bufB     = (u16*)alloc((size_t)N_NODES * DIM * 2);
    float* a_s      = (float*)alloc((size_t)N_NODES * 4);
    float* a_d      = (float*)alloc((size_t)N_NODES * 4);
    float* p1       = (float*)alloc((size_t)NPOOL * L1DIM * 4);
    float* p2       = (float*)alloc((size_t)NPOOL * L2DIM * 4);
    u16*   W1b      = (u16*)alloc((size_t)DIM * DIM * 2);
    u16*   W2b      = (u16*)alloc((size_t)DIM * DIM * 2);
    u16*   Wgb      = (u16*)alloc((size_t)HD3 * DIM * 2);
    u16*   L1b      = (u16*)alloc((size_t)L1DIM * L1K * 2);
    u16*   gb    = bufX;            // aliases, lifetimes disjoint
    u16*   hGb   = bufA;            // GAT output, bf16 (2000 x 2560 row-major view)
    float* skbuf = (float*)bufB;    // split-K partials 16.4 MB

    dim3 b256(256);
    // CSR build (5 kernels: hist, col-scan, top-scan, binscatter, fused build)
    k_hist<<<NBLK, b256, 0, stream>>>(ei, cnt);
    k_bscan_col<<<NB_BUCKETS, b256, 0, stream>>>(cnt, basep, btot);
    k_bscan_top<<<1, 512, 0, stream>>>(btot, bbase, row_ptr);
    k_binscatter<<<NBLK, b256, 0, stream>>>(ei, basep, bbase, pairs);
    k_build_csr<<<NB_BUCKETS, b256, 0, stream>>>(pairs, bbase, row_ptr, dinv, col_src);

    // all fp32->bf16 conversions in one launch
    k_f2b_all<<<(QTOT + 255) / 256, b256, 0, stream>>>(x, bufX, W1, W1b, W2, W2b, Wg, Wgb, L1, L1b);

    int nb = (N_NODES + 3) / 4;
    int gemm_nb = N_NODES / 64;   // 1250
    // SGConv stage 1
    k_prop_bf<<<nb, b256, 0, stream>>>(row_ptr, col_src, dinv, bufX, bufA);
    k_prop_bf<<<nb, b256, 0, stream>>>(row_ptr, col_src, dinv, bufA, bufB);
    k_gemm_mfma<8, true, true, false><<<gemm_nb, b256, 0, stream>>>(
        bufB, W1b, b1, bufA, nullptr, nullptr, nullptr, nullptr, N_NODES, DIM);
    // SGConv stage 2
    k_prop_bf<<<nb, b256, 0, stream>>>(row_ptr, col_src, dinv, bufA, bufB);
    k_prop_bf<<<nb, b256, 0, stream>>>(row_ptr, col_src, dinv, bufB, bufA);
    k_gemm_mfma<8, true, true, false><<<gemm_nb, b256, 0, stream>>>(
        bufA, W2b, b2, bufB, nullptr, nullptr, nullptr, nullptr, N_NODES, DIM);
    // GAT projection + fused attention scores: g -> gb, a_s/a_d from fp32 accumulators
    k_gemm_mfma<4, false, false, true><<<gemm_nb, b256, 0, stream>>>(
        bufB, Wgb, nullptr, gb, att_src, att_dst, a_s, a_d, N_NODES, DIM);
    k_gat<<<nb, b256, 0, stream>>>(row_ptr, col_src, gb, a_s, a_d, bg, hGb);
    // pool(40) + MLP head
    k_gemm_mfma_sk<8><<<dim3(32, 4, SPLITK), b256, 0, stream>>>(
        hGb, L1b, skbuf, NPOOL, L1DIM, L1K, L1K / SPLITK);
    k_splitk_reduce<<<(NPOOL * L1DIM / 4 + 255) / 256, b256, 0, stream>>>(skbuf, bl1, p1);
    k_gemm<64, 64, 32, 4, 4, true, true><<<dim3(32, 4), b256, 0, stream>>>(p1, L2, bl2, p2, NPOOL, L2DIM, L1DIM);
    k_linear<256, 10, true, true><<<(NPOOL * 10 + 255) / 256, b256, 0, stream>>>(p2, L3, bl3, out, NPOOL);
}

// Round 19
// 470.751 us; speedup vs baseline: 1.0873x; 1.0042x over previous
//
#include <hip/hip_runtime.h>

#define N_NODES 80000
#define N_EDGES 1280000
#define NNZ (N_EDGES + N_NODES)
#define DIM 128
#define HD3 64
#define GROUP 40
#define NPOOL (N_NODES / GROUP)   // 2000
#define L1DIM 512
#define L2DIM 256
#define OUTD 10
#define SPLITK 4
#define L1K (HD3 * GROUP)          // 2560

// bucket sort for CSR build
#define NB_BUCKETS ((N_NODES + 255) >> 8)              // 313
#define NB_PAD 320
#define EPB 8192
#define NBLK ((NNZ + EPB - 1) / EPB)                   // 167

// weight f2b segment sizes (float4 quads) — X is no longer converted
#define QW1 (DIM * DIM / 4)            // 4096
#define QW2 (DIM * DIM / 4)            // 4096
#define QWG (HD3 * DIM / 4)            // 2048
#define QL1 (L1DIM * L1K / 4)          // 327680
#define QWTOT (QW1 + QW2 + QWG + QL1)
#define F2B_NB ((QWTOT + 255) / 256)   // 1320

typedef unsigned int u32;
typedef unsigned short u16;
typedef __bf16 bf16x8 __attribute__((ext_vector_type(8)));
typedef float f32x4 __attribute__((ext_vector_type(4)));
typedef float f32x2 __attribute__((ext_vector_type(2)));

__device__ __forceinline__ float lrelu(float v, float s) { return v > 0.f ? v : s * v; }

__device__ __forceinline__ float b2f(u16 b) {
    u32 u = ((u32)b) << 16;
    float f; __builtin_memcpy(&f, &u, 4); return f;
}
__device__ __forceinline__ u16 f2b(float f) {
    u32 u; __builtin_memcpy(&u, &f, 4);
    return (u16)((u + 0x7fffu + ((u >> 16) & 1u)) >> 16);
}
__device__ __forceinline__ f32x2 bf2(u32 v) {
    f32x2 r;
    r.x = __uint_as_float(v << 16);
    r.y = __uint_as_float(v & 0xffff0000u);
    return r;
}
// pack 8 fp32 -> bf16x8 (RNE), for fp32-A MFMA fragments
__device__ __forceinline__ bf16x8 pack8(float4 f0, float4 f1) {
    union { bf16x8 v; u16 s[8]; } u;
    u.s[0] = f2b(f0.x); u.s[1] = f2b(f0.y); u.s[2] = f2b(f0.z); u.s[3] = f2b(f0.w);
    u.s[4] = f2b(f1.x); u.s[5] = f2b(f1.y); u.s[6] = f2b(f1.z); u.s[7] = f2b(f1.w);
    return u.v;
}

// ---------------- CSR build: two-level bucket sort (packed u32 pairs) ----------------
// pair encoding: bits [23:0] = src (< 2^17), bits [31:24] = dst & 255 (bucket-local)
// k_hist doubles as the weight fp32->bf16 converter (blocks >= NBLK).

__global__ __launch_bounds__(256) void k_hist(const int* __restrict__ ei, u32* __restrict__ cnt,
                                              const float* __restrict__ w1, u16* __restrict__ w1b,
                                              const float* __restrict__ w2, u16* __restrict__ w2b,
                                              const float* __restrict__ wg, u16* __restrict__ wgb,
                                              const float* __restrict__ l1, u16* __restrict__ l1b) {
    __shared__ u32 h[NB_PAD];
    if (blockIdx.x >= NBLK) {          // weight conversion blocks
        int i = (blockIdx.x - NBLK) * 256 + threadIdx.x;
        const float* src; u16* dst; int off;
        if (i < QW1)                   { src = w1; dst = w1b; off = i; }
        else if (i < QW1 + QW2)        { src = w2; dst = w2b; off = i - QW1; }
        else if (i < QW1 + QW2 + QWG)  { src = wg; dst = wgb; off = i - QW1 - QW2; }
        else if (i < QWTOT)            { src = l1; dst = l1b; off = i - QW1 - QW2 - QWG; }
        else return;
        float4 v = ((const float4*)src)[off];
        ushort4 o = { f2b(v.x), f2b(v.y), f2b(v.z), f2b(v.w) };
        ((ushort4*)dst)[off] = o;
        return;
    }
    for (int i = threadIdx.x; i < NB_PAD; i += 256) h[i] = 0;
    __syncthreads();
    int base = blockIdx.x * EPB;
    #pragma unroll 4
    for (int i = 0; i < EPB / 256; ++i) {
        int idx = base + i * 256 + threadIdx.x;
        if (idx < NNZ) {
            int d = (idx < N_EDGES) ? ei[N_EDGES + idx] : idx - N_EDGES;
            atomicAdd(&h[d >> 8], 1u);
        }
    }
    __syncthreads();
    for (int b = threadIdx.x; b < NB_BUCKETS; b += 256)
        cnt[blockIdx.x * NB_PAD + b] = h[b];
}

__global__ __launch_bounds__(256) void k_bscan_col(const u32* __restrict__ cnt,
                                                   u32* __restrict__ basep,
                                                   u32* __restrict__ btot) {
    int b = blockIdx.x, t = threadIdx.x;
    u32 v = (t < NBLK) ? cnt[t * NB_PAD + b] : 0;
    __shared__ u32 sm[256];
    sm[t] = v; __syncthreads();
    for (int off = 1; off < 256; off <<= 1) {
        u32 u = (t >= off) ? sm[t - off] : 0; __syncthreads();
        sm[t] += u; __syncthreads();
    }
    if (t < NBLK) basep[t * NB_PAD + b] = sm[t] - v;
    if (t == 255) btot[b] = sm[255];
}

__global__ __launch_bounds__(512) void k_bscan_top(const u32* __restrict__ btot,
                                                   u32* __restrict__ bbase,
                                                   int* __restrict__ row_ptr) {
    __shared__ u32 sm[512];
    int t = threadIdx.x;
    u32 v = (t < NB_BUCKETS) ? btot[t] : 0;
    sm[t] = v; __syncthreads();
    for (int off = 1; off < 512; off <<= 1) {
        u32 u = (t >= off) ? sm[t - off] : 0; __syncthreads();
        sm[t] += u; __syncthreads();
    }
    if (t < NB_BUCKETS) bbase[t] = sm[t] - v;
    if (t == NB_BUCKETS - 1) bbase[NB_BUCKETS] = sm[t];
    if (t == 0) row_ptr[N_NODES] = NNZ;
}

__global__ __launch_bounds__(256) void k_binscatter(const int* __restrict__ ei,
                                                    const u32* __restrict__ basep,
                                                    const u32* __restrict__ bbase,
                                                    u32* __restrict__ pairs) {
    __shared__ u32 rk[NB_PAD];
    for (int i = threadIdx.x; i < NB_PAD; i += 256) rk[i] = 0;
    __syncthreads();
    int base = blockIdx.x * EPB;
    #pragma unroll 4
    for (int i = 0; i < EPB / 256; ++i) {
        int idx = base + i * 256 + threadIdx.x;
        if (idx < NNZ) {
            int s, d;
            if (idx < N_EDGES) { s = ei[idx]; d = ei[N_EDGES + idx]; }
            else { s = idx - N_EDGES; d = s; }
            int b = d >> 8;
            u32 r = atomicAdd(&rk[b], 1u);
            u32 pos = bbase[b] + basep[blockIdx.x * NB_PAD + b] + r;
            pairs[pos] = ((u32)(d & 255) << 24) | (u32)s;
        }
    }
}

// Fused CSR tail: per bucket — count (LDS) -> local excl scan -> row_ptr + dinv ->
// rank-scatter col_src.
__global__ __launch_bounds__(256) void k_build_csr(const u32* __restrict__ pairs,
                                                   const u32* __restrict__ bbase,
                                                   int* __restrict__ row_ptr,
                                                   float* __restrict__ dinv,
                                                   int* __restrict__ col_src) {
    __shared__ u32 c[256], sc[256], ex[256];
    int t = threadIdx.x, b = blockIdx.x;
    int lo = bbase[b], hi = bbase[b + 1];
    c[t] = 0;
    __syncthreads();
    for (int i = lo + t; i < hi; i += 256)
        atomicAdd(&c[pairs[i] >> 24], 1u);
    __syncthreads();
    u32 cv = c[t];
    sc[t] = cv;
    __syncthreads();
    for (int off = 1; off < 256; off <<= 1) {
        u32 u = (t >= off) ? sc[t - off] : 0; __syncthreads();
        sc[t] += u; __syncthreads();
    }
    ex[t] = sc[t] - cv;
    int node = (b << 8) + t;
    if (node < N_NODES) {
        row_ptr[node] = lo + (int)ex[t];
        dinv[node] = rsqrtf((float)cv);
    }
    c[t] = 0;
    __syncthreads();
    for (int i = lo + t; i < hi; i += 256) {
        u32 p = pairs[i];
        u32 dl = p >> 24;
        u32 r = atomicAdd(&c[dl], 1u);
        col_src[lo + (int)ex[dl] + (int)r] = (int)(p & 0xFFFFFFu);
    }
}

// ---------------- propagation (bf16 storage, fp32 accum), 128-dim ----------------
// EPI: fuse bias + lrelu into the epilogue (bias/act of the preceding linear,
// valid because S-propagation commutes with the per-node linear map).

template<bool EPI>
__global__ __launch_bounds__(256) void k_prop_bf(const int* __restrict__ row_ptr,
                                                 const int* __restrict__ col_src,
                                                 const float* __restrict__ dinv,
                                                 const u16* __restrict__ hin,
                                                 u16* __restrict__ hout,
                                                 const float* __restrict__ bias) {
    int lane = threadIdx.x & 63;
    int node = blockIdx.x * 4 + (threadIdx.x >> 6);
    if (node >= N_NODES) return;
    int j0 = row_ptr[node], j1 = row_ptr[node + 1];
    float dn = dinv[node];
    const int grp = lane >> 4;      // edge group 0..3
    const int dl  = lane & 15;      // dim slot: dims dl*8 .. dl*8+7
    f32x2 acc[4] = {};

    for (int base = j0; base < j1; base += 64) {
        int cnt = j1 - base; if (cnt > 64) cnt = 64;
        int jj = base + lane;
        int sidx = (jj < j1) ? col_src[jj] : 0;
        int l = 0;
        for (; l + 16 <= cnt; l += 16) {
            uint4 v[4]; f32x2 w2[4];
            #pragma unroll
            for (int q = 0; q < 4; ++q) {
                int s = __shfl(sidx, l + q * 4 + grp);
                float wq = dinv[s] * dn;
                w2[q].x = wq; w2[q].y = wq;
                v[q] = *(const uint4*)(hin + (size_t)s * DIM + dl * 8);
            }
            #pragma unroll
            for (int q = 0; q < 4; ++q) {
                acc[0] = __builtin_elementwise_fma(bf2(v[q].x), w2[q], acc[0]);
                acc[1] = __builtin_elementwise_fma(bf2(v[q].y), w2[q], acc[1]);
                acc[2] = __builtin_elementwise_fma(bf2(v[q].z), w2[q], acc[2]);
                acc[3] = __builtin_elementwise_fma(bf2(v[q].w), w2[q], acc[3]);
            }
        }
        for (; l + 4 <= cnt; l += 4) {
            int s = __shfl(sidx, l + grp);
            float wq = dinv[s] * dn;
            f32x2 w2; w2.x = wq; w2.y = wq;
            uint4 v = *(const uint4*)(hin + (size_t)s * DIM + dl * 8);
            acc[0] = __builtin_elementwise_fma(bf2(v.x), w2, acc[0]);
            acc[1] = __builtin_elementwise_fma(bf2(v.y), w2, acc[1]);
            acc[2] = __builtin_elementwise_fma(bf2(v.z), w2, acc[2]);
            acc[3] = __builtin_elementwise_fma(bf2(v.w), w2, acc[3]);
        }
        for (; l < cnt; ++l) {
            int s = __shfl(sidx, l);
            if (grp == 0) {
                float wq = dinv[s] * dn;
                f32x2 w2; w2.x = wq; w2.y = wq;
                uint4 v = *(const uint4*)(hin + (size_t)s * DIM + dl * 8);
                acc[0] = __builtin_elementwise_fma(bf2(v.x), w2, acc[0]);
                acc[1] = __builtin_elementwise_fma(bf2(v.y), w2, acc[1]);
                acc[2] = __builtin_elementwise_fma(bf2(v.z), w2, acc[2]);
                acc[3] = __builtin_elementwise_fma(bf2(v.w), w2, acc[3]);
            }
        }
    }
    #pragma unroll
    for (int d = 0; d < 4; ++d) {
        acc[d].x += __shfl_xor(acc[d].x, 16); acc[d].x += __shfl_xor(acc[d].x, 32);
        acc[d].y += __shfl_xor(acc[d].y, 16); acc[d].y += __shfl_xor(acc[d].y, 32);
    }
    if (grp == 0) {
        if (EPI) {
            float4 b0 = *(const float4*)(bias + dl * 8);
            float4 b4 = *(const float4*)(bias + dl * 8 + 4);
            acc[0].x = lrelu(acc[0].x + b0.x, 0.1f); acc[0].y = lrelu(acc[0].y + b0.y, 0.1f);
            acc[1].x = lrelu(acc[1].x + b0.z, 0.1f); acc[1].y = lrelu(acc[1].y + b0.w, 0.1f);
            acc[2].x = lrelu(acc[2].x + b4.x, 0.1f); acc[2].y = lrelu(acc[2].y + b4.y, 0.1f);
            acc[3].x = lrelu(acc[3].x + b4.z, 0.1f); acc[3].y = lrelu(acc[3].y + b4.w, 0.1f);
        }
        uint4 o;
        o.x = (u32)f2b(acc[0].x) | ((u32)f2b(acc[0].y) << 16);
        o.y = (u32)f2b(acc[1].x) | ((u32)f2b(acc[1].y) << 16);
        o.z = (u32)f2b(acc[2].x) | ((u32)f2b(acc[2].y) << 16);
        o.w = (u32)f2b(acc[3].x) | ((u32)f2b(acc[3].y) << 16);
        *(uint4*)(hout + (size_t)node * DIM + dl * 8) = o;
    }
}

// ---------------- MFMA GEMM: C = A W^T, bf16 out; optional fp32 A / fused attn ----------------

template<int NT, bool ATTN, bool F32A>
__global__ __launch_bounds__(256) void k_gemm_mfma(const u16* __restrict__ A,
                                                   const float* __restrict__ Af,
                                                   const u16* __restrict__ Wb,
                                                   u16* __restrict__ C,
                                                   const float* __restrict__ att_src,
                                                   const float* __restrict__ att_dst,
                                                   float* __restrict__ a_s,
                                                   float* __restrict__ a_d,
                                                   int M, int K) {
    const int lane = threadIdx.x & 63;
    const int wave = threadIdx.x >> 6;
    const int m0 = blockIdx.x * 64 + wave * 16;
    const int row = lane & 15, kg = lane >> 4;
    const int Ntot = NT * 16;

    const u16* Apb = F32A ? nullptr : A + (size_t)(m0 + row) * K + kg * 8;
    const float* Apf = F32A ? Af + (size_t)(m0 + row) * K + kg * 8 : nullptr;
    f32x4 acc[NT] = {};

    for (int k0 = 0; k0 < K; k0 += 32) {
        bf16x8 a;
        if (F32A) {
            float4 f0 = *(const float4*)(Apf + k0);
            float4 f1 = *(const float4*)(Apf + k0 + 4);
            a = pack8(f0, f1);
        } else {
            a = *(const bf16x8*)(Apb + k0);
        }
        #pragma unroll
        for (int nt = 0; nt < NT; ++nt) {
            const u16* Wp = Wb + (size_t)(nt * 16 + row) * K + k0 + kg * 8;
            bf16x8 bb = *(const bf16x8*)Wp;
            acc[nt] = __builtin_amdgcn_mfma_f32_16x16x32_bf16(a, bb, acc[nt], 0, 0, 0);
        }
    }

    #pragma unroll
    for (int nt = 0; nt < NT; ++nt) {
        #pragma unroll
        for (int r = 0; r < 4; ++r) {
            int crow = m0 + kg * 4 + r;
            C[(size_t)crow * Ntot + nt * 16 + row] = f2b(acc[nt][r]);
        }
    }

    if (ATTN) {
        float s1[4] = {}, s2[4] = {};
        #pragma unroll
        for (int nt = 0; nt < NT; ++nt) {
            float as = att_src[nt * 16 + row];
            float av = att_dst[nt * 16 + row];
            #pragma unroll
            for (int r = 0; r < 4; ++r) {
                s1[r] += acc[nt][r] * as;
                s2[r] += acc[nt][r] * av;
            }
        }
        #pragma unroll
        for (int r = 0; r < 4; ++r) {
            #pragma unroll
            for (int off = 1; off < 16; off <<= 1) {
                s1[r] += __shfl_xor(s1[r], off);
                s2[r] += __shfl_xor(s2[r], off);
            }
        }
        if (row == 0) {
            #pragma unroll
            for (int r = 0; r < 4; ++r) {
                a_s[m0 + kg * 4 + r] = s1[r];
                a_d[m0 + kg * 4 + r] = s2[r];
            }
        }
    }
}

// ---------------- MFMA split-K GEMM (MLP L1) ----------------

template<int NT>
__global__ __launch_bounds__(256) void k_gemm_mfma_sk(const u16* __restrict__ A,
                                                      const u16* __restrict__ Wb,
                                                      float* __restrict__ C,
                                                      int M, int Ntot, int K, int kChunk) {
    const int lane = threadIdx.x & 63;
    const int wave = threadIdx.x >> 6;
    const int m0 = blockIdx.x * 64 + wave * 16;
    const int row = lane & 15, kg = lane >> 4;
    const int n0 = blockIdx.y * NT * 16;
    const int kBeg = blockIdx.z * kChunk;

    int arow = m0 + row; if (arow >= M) arow = M - 1;
    const u16* Ap = A + (size_t)arow * K + kg * 8;
    f32x4 acc[NT] = {};

    for (int k0 = kBeg; k0 < kBeg + kChunk; k0 += 32) {
        bf16x8 a = *(const bf16x8*)(Ap + k0);
        #pragma unroll
        for (int nt = 0; nt < NT; ++nt) {
            const u16* Wp = Wb + (size_t)(n0 + nt * 16 + row) * K + k0 + kg * 8;
            bf16x8 bb = *(const bf16x8*)Wp;
            acc[nt] = __builtin_amdgcn_mfma_f32_16x16x32_bf16(a, bb, acc[nt], 0, 0, 0);
        }
    }

    float* Cp = C + (size_t)blockIdx.z * M * Ntot;
    #pragma unroll
    for (int nt = 0; nt < NT; ++nt) {
        #pragma unroll
        for (int r = 0; r < 4; ++r) {
            int crow = m0 + kg * 4 + r;
            if (crow < M) Cp[(size_t)crow * Ntot + n0 + nt * 16 + row] = acc[nt][r];
        }
    }
}

// ---------------- GEMM fp32 (MLP tail) ----------------

template<int BM, int BN, int BK, int TM, int TN, bool BIAS, bool ACT>
__global__ __launch_bounds__(256) void k_gemm(const float* __restrict__ A,
                                              const float* __restrict__ W,
                                              const float* __restrict__ b,
                                              float* __restrict__ C,
                                              int M, int Ntot, int K) {
    __shared__ float As[BK][BM + 4];
    __shared__ float Bs[BK][BN + 4];
    const int t = threadIdx.x;
    const int m0 = blockIdx.x * BM, n0 = blockIdx.y * BN;
    const int ty = t / (BN / TN), tx = t % (BN / TN);

    float acc[TM][TN] = {};

    for (int k0 = 0; k0 < K; k0 += BK) {
        #pragma unroll
        for (int p = 0; p < BM * BK / 4 / 256; ++p) {
            int id = p * 256 + t;
            int m = id % BM, kk = (id / BM) * 4;
            float4 v = {0.f, 0.f, 0.f, 0.f};
            if (m0 + m < M) v = *(const float4*)(A + (size_t)(m0 + m) * K + k0 + kk);
            As[kk + 0][m] = v.x; As[kk + 1][m] = v.y;
            As[kk + 2][m] = v.z; As[kk + 3][m] = v.w;
        }
        #pragma unroll
        for (int p = 0; p < BN * BK / 4 / 256; ++p) {
            int id = p * 256 + t;
            int n = id % BN, kk = (id / BN) * 4;
            float4 v = *(const float4*)(W + (size_t)(n0 + n) * K + k0 + kk);
            Bs[kk + 0][n] = v.x; Bs[kk + 1][n] = v.y;
            Bs[kk + 2][n] = v.z; Bs[kk + 3][n] = v.w;
        }
        __syncthreads();

        #pragma unroll
        for (int k = 0; k < BK; ++k) {
            float a[TM], bb[TN];
            #pragma unroll
            for (int i = 0; i < TM; ++i) a[i] = As[k][ty * TM + i];
            #pragma unroll
            for (int j = 0; j < TN; ++j) bb[j] = Bs[k][tx * TN + j];
            #pragma unroll
            for (int i = 0; i < TM; ++i)
                #pragma unroll
                for (int j = 0; j < TN; ++j)
                    acc[i][j] += a[i] * bb[j];
        }
        __syncthreads();
    }

    #pragma unroll
    for (int i = 0; i < TM; ++i) {
        int row = m0 + ty * TM + i;
        if (row >= M) continue;
        float4 o;
        float* op = (float*)&o;
        #pragma unroll
        for (int j = 0; j < TN; ++j) {
            float r = acc[i][j];
            if (BIAS) r += b[n0 + tx * TN + j];
            if (ACT) r = lrelu(r, 0.1f);
            op[j] = r;
        }
        *(float4*)(C + (size_t)row * Ntot + n0 + tx * TN) = o;
    }
}

__global__ __launch_bounds__(256) void k_splitk_reduce(const float* __restrict__ part,
                                                       const float* __restrict__ b,
                                                       float* __restrict__ out) {
    const int total4 = NPOOL * L1DIM / 4;
    int idx = blockIdx.x * blockDim.x + threadIdx.x;
    if (idx >= total4) return;
    const size_t stride4 = (size_t)NPOOL * L1DIM / 4;
    const float4* p4 = (const float4*)part;
    float4 s = p4[idx];
    #pragma unroll
    for (int z = 1; z < SPLITK; ++z) {
        float4 v = p4[idx + z * stride4];
        s.x += v.x; s.y += v.y; s.z += v.z; s.w += v.w;
    }
    int col = (idx * 4) % L1DIM;
    float4 bb = *(const float4*)(b + col);
    s.x = lrelu(s.x + bb.x, 0.1f); s.y = lrelu(s.y + bb.y, 0.1f);
    s.z = lrelu(s.z + bb.z, 0.1f); s.w = lrelu(s.w + bb.w, 0.1f);
    ((float4*)out)[idx] = s;
}

// ---------------- tiny final linear ----------------

template<int KD, int OD, bool BIAS, bool ACT>
__global__ void k_linear(const float* __restrict__ in, const float* __restrict__ W,
                         const float* __restrict__ b, float* __restrict__ out, int nrows) {
    int idx = blockIdx.x * blockDim.x + threadIdx.x;
    int n = idx / OD, o = idx % OD;
    if (n >= nrows) return;
    const float4* ar = (const float4*)(in + (size_t)n * KD);
    const float4* wr = (const float4*)(W + (size_t)o * KD);
    float4 acc = {0.f, 0.f, 0.f, 0.f};
    #pragma unroll 8
    for (int k = 0; k < KD / 4; ++k) {
        float4 a = ar[k], w = wr[k];
        acc.x += a.x * w.x; acc.y += a.y * w.y;
        acc.z += a.z * w.z; acc.w += a.w * w.w;
    }
    float r = (acc.x + acc.y) + (acc.z + acc.w);
    if (BIAS) r += b[o];
    if (ACT) r = lrelu(r, 0.1f);
    out[idx] = r;
}

// ---------------- GAT: online softmax + 16-lane-group aggregation, bf16 out ----------------

__global__ __launch_bounds__(256) void k_gat(const int* __restrict__ row_ptr,
                                             const int* __restrict__ col_src,
                                             const u16* __restrict__ g,
                                             const float* __restrict__ a_s,
                                             const float* __restrict__ a_d,
                                             const float* __restrict__ bg,
                                             u16* __restrict__ hout) {
    __shared__ float wbuf[4][64];
    int lane = threadIdx.x & 63;
    int wid  = threadIdx.x >> 6;
    int node = blockIdx.x * 4 + wid;
    if (node >= N_NODES) return;
    int j0 = row_ptr[node], j1 = row_ptr[node + 1];
    float ad = a_d[node];
    const int grp = lane >> 4, dl = lane & 15;   // dims dl*4 .. dl*4+3
    float m = -1e30f, den = 0.f;
    f32x2 acc[2] = {};

    for (int base = j0; base < j1; base += 64) {
        int cnt = j1 - base; if (cnt > 64) cnt = 64;
        int jj = base + lane;
        int sidx = 0;
        float e = -1e30f;
        if (jj < j1) { sidx = col_src[jj]; e = lrelu(a_s[sidx] + ad, 0.2f); }
        float cm = e;
        for (int off = 32; off; off >>= 1) cm = fmaxf(cm, __shfl_xor(cm, off));
        float nm = fmaxf(m, cm);
        float scale = __expf(m - nm);
        float wv = (jj < j1) ? __expf(e - nm) : 0.f;
        wbuf[wid][lane] = wv;
        float cden = wv;
        for (int off = 32; off; off >>= 1) cden += __shfl_xor(cden, off);
        den = den * scale + cden;
        f32x2 sc2; sc2.x = scale; sc2.y = scale;
        acc[0] *= sc2; acc[1] *= sc2;
        m = nm;
        int l = 0;
        for (; l + 16 <= cnt; l += 16) {
            uint2 v[4]; f32x2 w2[4];
            #pragma unroll
            for (int q = 0; q < 4; ++q) {
                int e2 = l + q * 4 + grp;
                int s = __shfl(sidx, e2);
                float wq = wbuf[wid][e2];
                w2[q].x = wq; w2[q].y = wq;
                v[q] = *(const uint2*)(g + (size_t)s * HD3 + dl * 4);
            }
            #pragma unroll
            for (int q = 0; q < 4; ++q) {
                acc[0] = __builtin_elementwise_fma(bf2(v[q].x), w2[q], acc[0]);
                acc[1] = __builtin_elementwise_fma(bf2(v[q].y), w2[q], acc[1]);
            }
        }
        for (; l + 4 <= cnt; l += 4) {
            int e2 = l + grp;
            int s = __shfl(sidx, e2);
            float wq = wbuf[wid][e2];
            f32x2 w2; w2.x = wq; w2.y = wq;
            uint2 v = *(const uint2*)(g + (size_t)s * HD3 + dl * 4);
            acc[0] = __builtin_elementwise_fma(bf2(v.x), w2, acc[0]);
            acc[1] = __builtin_elementwise_fma(bf2(v.y), w2, acc[1]);
        }
        for (; l < cnt; ++l) {
            int s = __shfl(sidx, l);
            if (grp == 0) {
                float wq = wbuf[wid][l];
                f32x2 w2; w2.x = wq; w2.y = wq;
                uint2 v = *(const uint2*)(g + (size_t)s * HD3 + dl * 4);
                acc[0] = __builtin_elementwise_fma(bf2(v.x), w2, acc[0]);
                acc[1] = __builtin_elementwise_fma(bf2(v.y), w2, acc[1]);
            }
        }
    }
    #pragma unroll
    for (int d = 0; d < 2; ++d) {
        acc[d].x += __shfl_xor(acc[d].x, 16); acc[d].x += __shfl_xor(acc[d].x, 32);
        acc[d].y += __shfl_xor(acc[d].y, 16); acc[d].y += __shfl_xor(acc[d].y, 32);
    }
    if (grp == 0) {
        float r0 = lrelu(acc[0].x / den + bg[dl * 4 + 0], 0.1f);
        float r1 = lrelu(acc[0].y / den + bg[dl * 4 + 1], 0.1f);
        float r2 = lrelu(acc[1].x / den + bg[dl * 4 + 2], 0.1f);
        float r3 = lrelu(acc[1].y / den + bg[dl * 4 + 3], 0.1f);
        uint2 o;
        o.x = (u32)f2b(r0) | ((u32)f2b(r1) << 16);
        o.y = (u32)f2b(r2) | ((u32)f2b(r3) << 16);
        *(uint2*)(hout + (size_t)node * HD3 + dl * 4) = o;
    }
}

// ---------------- launch ----------------

extern "C" void kernel_launch(void* const* d_in, const int* in_sizes, int n_in,
                              void* d_out, int out_size, void* d_ws, size_t ws_size,
                              hipStream_t stream) {
    const float* x   = (const float*)d_in[0];
    const int*   ei  = (const int*)d_in[1];
    const float* W1  = (const float*)d_in[2];
    const float* b1  = (const float*)d_in[3];
    const float* W2  = (const float*)d_in[4];
    const float* b2  = (const float*)d_in[5];
    const float* Wg  = (const float*)d_in[6];
    const float* att_src = (const float*)d_in[7];
    const float* att_dst = (const float*)d_in[8];
    const float* bg  = (const float*)d_in[9];
    const float* L1  = (const float*)d_in[10];
    const float* bl1 = (const float*)d_in[11];
    const float* L2  = (const float*)d_in[12];
    const float* bl2 = (const float*)d_in[13];
    const float* L3  = (const float*)d_in[14];
    const float* bl3 = (const float*)d_in[15];
    float* out = (float*)d_out;

    char* w = (char*)d_ws;
    auto alloc = [&](size_t bytes) {
        char* p = w;
        w += (bytes + 255) & ~(size_t)255;
        return p;
    };
    int*   row_ptr  = (int*)alloc((size_t)(N_NODES + 1) * 4);
    float* dinv     = (float*)alloc((size_t)N_NODES * 4);
    int*   col_src  = (int*)alloc((size_t)NNZ * 4);
    u32*   pairs    = (u32*)alloc((size_t)NNZ * 4);
    u32*   cnt      = (u32*)alloc((size_t)NBLK * NB_PAD * 4);
    u32*   basep    = (u32*)alloc((size_t)NBLK * NB_PAD * 4);
    u32*   btot     = (u32*)alloc((size_t)NB_PAD * 4);
    u32*   bbase    = (u32*)alloc((size_t)(NB_BUCKETS + 1) * 4);
    u16*   bufA     = (u16*)alloc((size_t)N_NODES * DIM * 2);
    u16*   bufB     = (u16*)alloc((size_t)N_NODES * DIM * 2);
    u16*   bufC     = (u16*)alloc((size_t)N_NODES * DIM * 2);
    float* a_s      = (float*)alloc((size_t)N_NODES * 4);
    float* a_d      = (float*)alloc((size_t)N_NODES * 4);
    float* p1       = (float*)alloc((size_t)NPOOL * L1DIM * 4);
    float* p2       = (float*)alloc((size_t)NPOOL * L2DIM * 4);
    u16*   W1b      = (u16*)alloc((size_t)DIM * DIM * 2);
    u16*   W2b      = (u16*)alloc((size_t)DIM * DIM * 2);
    u16*   Wgb      = (u16*)alloc((size_t)HD3 * DIM * 2);
    u16*   L1b      = (u16*)alloc((size_t)L1DIM * L1K * 2);
    u16*   gb    = bufA;            // aliases, lifetimes disjoint
    u16*   hGb   = bufC;            // GAT output, bf16 (2000 x 2560 row-major view)
    float* skbuf = (float*)bufB;    // split-K partials 16.4 MB (h2 consumed by G3)

    dim3 b256(256);
    // CSR build (hist doubles as weight f2b)
    k_hist<<<NBLK + F2B_NB, b256, 0, stream>>>(ei, cnt, W1, W1b, W2, W2b, Wg, Wgb, L1, L1b);
    k_bscan_col<<<NB_BUCKETS, b256, 0, stream>>>(cnt, basep, btot);
    k_bscan_top<<<1, 512, 0, stream>>>(btot, bbase, row_ptr);
    k_binscatter<<<NBLK, b256, 0, stream>>>(ei, basep, bbase, pairs);
    k_build_csr<<<NB_BUCKETS, b256, 0, stream>>>(pairs, bbase, row_ptr, dinv, col_src);

    int nb = (N_NODES + 3) / 4;
    int gemm_nb = N_NODES / 64;   // 1250
    // SGConv stage 1 (reordered: (S^2 X) W1 == S^2 (X W1); bias+lrelu in prop epilogue)
    k_gemm_mfma<8, false, true><<<gemm_nb, b256, 0, stream>>>(
        nullptr, x, W1b, bufA, nullptr, nullptr, nullptr, nullptr, N_NODES, DIM);
    k_prop_bf<false><<<nb, b256, 0, stream>>>(row_ptr, col_src, dinv, bufA, bufB, nullptr);
    k_prop_bf<true><<<nb, b256, 0, stream>>>(row_ptr, col_src, dinv, bufB, bufA, b1);   // h1
    // SGConv stage 2
    k_gemm_mfma<8, false, false><<<gemm_nb, b256, 0, stream>>>(
        bufA, nullptr, W2b, bufB, nullptr, nullptr, nullptr, nullptr, N_NODES, DIM);
    k_prop_bf<false><<<nb, b256, 0, stream>>>(row_ptr, col_src, dinv, bufB, bufA, nullptr);
    k_prop_bf<true><<<nb, b256, 0, stream>>>(row_ptr, col_src, dinv, bufA, bufB, b2);   // h2
    // GAT projection + fused attention scores: g -> gb (bufA), a_s/a_d from fp32 acc
    k_gemm_mfma<4, true, false><<<gemm_nb, b256, 0, stream>>>(
        bufB, nullptr, Wgb, gb, att_src, att_dst, a_s, a_d, N_NODES, DIM);
    k_gat<<<nb, b256, 0, stream>>>(row_ptr, col_src, gb, a_s, a_d, bg, hGb);
    // pool(40) + MLP head
    k_gemm_mfma_sk<8><<<dim3(32, 4, SPLITK), b256, 0, stream>>>(
        hGb, L1b, skbuf, NPOOL, L1DIM, L1K, L1K / SPLITK);
    k_splitk_reduce<<<(NPOOL * L1DIM / 4 + 255) / 256, b256, 0, stream>>>(skbuf, bl1, p1);
    k_gemm<64, 64, 32, 4, 4, true, true><<<dim3(32, 4), b256, 0, stream>>>(p1, L2, bl2, p2, NPOOL, L2DIM, L1DIM);
    k_linear<256, 10, true, true><<<(NPOOL * 10 + 255) / 256, b256, 0, stream>>>(p2, L3, bl3, out, NPOOL);
}